// Round 10
// baseline (704.468 us; speedup 1.0000x reference)
//
#include <hip/hip_runtime.h>
#include <hip/hip_bf16.h>

#define CB 32
#define CN 1024
#define CE 512
#define CD 300
#define EP 320    // padded edge-row stride (floats); pad cols [300,320) are written 0
#define MCAP 192  // member-list capacity per edge (deg ~ B(1024,.1): mean 102, sd 9.6)
#define NCAP 96   // edge-list capacity per node (deg ~ B(512,.1): mean 51.2, sd 6.8)

// ---------- embedding gather: X[r,:] = emb[idx[r],:] ----------
__global__ void k_embed(const int* __restrict__ idx, const float* __restrict__ emb,
                        float* __restrict__ X) {
    int gid = blockIdx.x * blockDim.x + threadIdx.x;
    const int total = CB * CN * 75;
    if (gid >= total) return;
    int r = gid / 75, c = gid % 75;
    int e = idx[r];
    reinterpret_cast<float4*>(X)[(size_t)r * 75 + c] =
        reinterpret_cast<const float4*>(emb)[(size_t)e * 75 + c];
}

// ---------- ebits[b*E+e][c] = ballot(HT[b,e,c*64+lane] != 0) ----------
__global__ void k_ebits(const int* __restrict__ HT, unsigned long long* __restrict__ ebits) {
    int gw = (blockIdx.x * blockDim.x + threadIdx.x) >> 6;   // b*CE+e
    int lane = threadIdx.x & 63;
    const int* hrow = HT + (size_t)gw * CN;
#pragma unroll
    for (int c = 0; c < 16; ++c) {
        unsigned long long bal = __ballot(hrow[(c << 6) + lane] != 0);
        if (lane == 0) ebits[(size_t)gw * 16 + c] = bal;
    }
}

// ---------- nbits = bit-transpose of ebits ----------
__global__ __launch_bounds__(512) void k_bitT(const unsigned long long* __restrict__ ebits,
        unsigned long long* __restrict__ nbits) {
    __shared__ unsigned long long w[8][64];
    int b = blockIdx.x >> 4, nc = blockIdx.x & 15;
    int tid = threadIdx.x, ec = tid >> 6, lane = tid & 63;
    w[ec][lane] = ebits[((size_t)b * CE + (ec << 6) + lane) * 16 + nc];
    __syncthreads();
    unsigned long long out = 0;
#pragma unroll
    for (int j = 0; j < 64; ++j)
        out |= ((w[ec][j] >> lane) & 1ull) << j;
    nbits[((size_t)b * CN + (nc << 6) + lane) * 8 + ec] = out;
}

// ---------- member lists (edge side): mem[gw][0..deg) ascending node ids ----------
__global__ void k_members(const unsigned long long* __restrict__ ebits,
                          unsigned short* __restrict__ mem, int* __restrict__ degs) {
    int gw = (blockIdx.x * blockDim.x + threadIdx.x) >> 6;
    int lane = threadIdx.x & 63;
    const unsigned long long* eb = ebits + (size_t)gw * 16;
    unsigned short* lst = mem + (size_t)gw * MCAP;
    int base = 0;
    unsigned long long lmask = (1ull << lane) - 1ull;
#pragma unroll
    for (int c = 0; c < 16; ++c) {
        unsigned long long w = eb[c];
        if ((w >> lane) & 1ull) {
            int off = base + (int)__popcll(w & lmask);
            if (off < MCAP) lst[off] = (unsigned short)((c << 6) + lane);
        }
        base += (int)__popcll(w);
    }
    if (lane == 0) degs[gw] = base;
}

// ---------- edge lists (node side): nmem[node][0..deg) ascending edge ids ----------
__global__ void k_nmem(const unsigned long long* __restrict__ nbits,
                       unsigned short* __restrict__ nmem, int* __restrict__ ndegs) {
    int row = (blockIdx.x * blockDim.x + threadIdx.x) >> 6;   // b*CN+n
    int lane = threadIdx.x & 63;
    const unsigned long long* nb = nbits + (size_t)row * 8;
    unsigned short* lst = nmem + (size_t)row * NCAP;
    int base = 0;
    unsigned long long lmask = (1ull << lane) - 1ull;
#pragma unroll
    for (int c = 0; c < 8; ++c) {
        unsigned long long w = nb[c];
        if ((w >> lane) & 1ull) {
            int off = base + (int)__popcll(w & lmask);
            if (off < NCAP) lst[off] = (unsigned short)((c << 6) + lane);
        }
        base += (int)__popcll(w);
    }
    if (lane == 0) ndegs[row] = base;
}

// ---------- k_prep: vecs = 6 folded attention vectors ----------
__global__ void k_prep(const float* __restrict__ w2_1, const float* __restrict__ w3_1,
                       const float* __restrict__ a_1, const float* __restrict__ a2_1,
                       const float* __restrict__ w2_2, const float* __restrict__ w3_2,
                       const float* __restrict__ a_2, const float* __restrict__ a2_2,
                       float* __restrict__ vecs) {
    int which = blockIdx.x;
    int t = threadIdx.x;
    if (t >= CD) return;
    const float* W; const float* v;
    switch (which) {
        case 0:  W = w2_1; v = a_1 + CD;  break;
        case 1:  W = w2_1; v = a2_1;      break;
        case 2:  W = w3_1; v = a2_1 + CD; break;
        case 3:  W = w2_2; v = a_2 + CD;  break;
        case 4:  W = w2_2; v = a2_2;      break;
        default: W = w3_2; v = a2_2 + CD; break;
    }
    float s = 0.f;
    for (int j = 0; j < CD; ++j) s += W[(size_t)t * CD + j] * v[j];
    vecs[which * CD + t] = s;
}

// ---------- C[M,300] = A[M,300(lda)] @ W[300,300] ----------
__global__ __launch_bounds__(256) void k_gemm300(const float* __restrict__ A,
                                                 const float* __restrict__ W,
                                                 float* __restrict__ C, int M,
                                                 int lda, int ldc) {
    __shared__ float As[64][20];
    __shared__ float Ws[16][68];
    int tid = threadIdx.x;
    int n0 = blockIdx.x * 64, m0 = blockIdx.y * 64;
    int tx = tid & 15, ty = tid >> 4;
    int la_r = tid >> 2, la_c = (tid & 3) << 2;
    int lw_r = tid >> 4, lw_c = (tid & 15) << 2;
    float acc[4][4] = {};
    for (int k0 = 0; k0 < CD; k0 += 16) {
        {
            int kc = k0 + la_c;
            const float* Ap = A + (size_t)(m0 + la_r) * lda + kc;
            float4 av;
            if (kc + 3 < CD) av = *reinterpret_cast<const float4*>(Ap);
            else {
                av.x = kc     < CD ? Ap[0] : 0.f;
                av.y = kc + 1 < CD ? Ap[1] : 0.f;
                av.z = kc + 2 < CD ? Ap[2] : 0.f;
                av.w = 0.f;
            }
            *reinterpret_cast<float4*>(&As[la_r][la_c]) = av;
        }
        {
            int kr = k0 + lw_r;
            float4 wv = {0.f, 0.f, 0.f, 0.f};
            if (kr < CD) {
                const float* Wp = W + (size_t)kr * CD + n0 + lw_c;
                if (n0 + lw_c + 3 < CD) wv = *reinterpret_cast<const float4*>(Wp);
                else {
                    if (n0 + lw_c     < CD) wv.x = Wp[0];
                    if (n0 + lw_c + 1 < CD) wv.y = Wp[1];
                    if (n0 + lw_c + 2 < CD) wv.z = Wp[2];
                }
            }
            *reinterpret_cast<float4*>(&Ws[lw_r][lw_c]) = wv;
        }
        __syncthreads();
#pragma unroll
        for (int k = 0; k < 16; ++k) {
            float av[4];
#pragma unroll
            for (int i = 0; i < 4; ++i) av[i] = As[ty * 4 + i][k];
            float4 bv = *reinterpret_cast<const float4*>(&Ws[k][tx * 4]);
            float bb[4] = {bv.x, bv.y, bv.z, bv.w};
#pragma unroll
            for (int i = 0; i < 4; ++i)
#pragma unroll
                for (int j = 0; j < 4; ++j) acc[i][j] += av[i] * bb[j];
        }
        __syncthreads();
    }
    for (int i = 0; i < 4; ++i) {
        int m = m0 + ty * 4 + i;
        int n = n0 + tx * 4;
        float* Cp = C + (size_t)m * ldc + n;
        if (n + 3 < CD) {
            float4 v = {acc[i][0], acc[i][1], acc[i][2], acc[i][3]};
            *reinterpret_cast<float4*>(Cp) = v;
        } else {
            for (int j = 0; j < 4; ++j) if (n + j < CD) Cp[j] = acc[i][j];
        }
    }
}

// ---------- s1[r] = leaky(wc·a_top + X[r,:]·av), p[r] = X[r,:]·pv ----------
__global__ void k_score(const float* __restrict__ X, const float* __restrict__ av,
                        const float* __restrict__ pv, const float* __restrict__ wc,
                        const float* __restrict__ a_orig,
                        float alpha, float* __restrict__ s1, float* __restrict__ p, int M) {
    int gw = (blockIdx.x * blockDim.x + threadIdx.x) >> 6;
    int lane = threadIdx.x & 63;
    if (gw >= M) return;
    const float* row = X + (size_t)gw * CD;
    float d1 = 0.f, d2 = 0.f, dc = 0.f;
    for (int d = lane; d < CD; d += 64) {
        float x = row[d];
        d1 += x * av[d];
        d2 += x * pv[d];
        dc += wc[d] * a_orig[d];
    }
    for (int o = 32; o; o >>= 1) {
        d1 += __shfl_down(d1, o);
        d2 += __shfl_down(d2, o);
        dc += __shfl_down(dc, o);
    }
    if (lane == 0) {
        float v = dc + d1;
        s1[gw] = v > 0.f ? v : alpha * v;
        p[gw] = d2;
    }
}

// ---------- per-batch max over s1, e1 = exp(s1 - max) ----------
__global__ __launch_bounds__(1024) void k_bmax(const float* __restrict__ s1,
                                               float* __restrict__ e1) {
    __shared__ float red[16];
    int b = blockIdx.x, t = threadIdx.x;
    float v = s1[b * CN + t];
    float m = v;
    for (int o = 32; o; o >>= 1) m = fmaxf(m, __shfl_xor(m, o));
    if ((t & 63) == 0) red[t >> 6] = m;
    __syncthreads();
    if (t == 0) {
        float mm = red[0];
        for (int i = 1; i < 16; ++i) mm = fmaxf(mm, red[i]);
        red[0] = mm;
    }
    __syncthreads();
    e1[b * CN + t] = __expf(v - red[0]);
}

// ---------- sparse edge aggregation + fused q (CSR member list, unroll-4) ----------
__global__ __launch_bounds__(256) void k_edge_agg(const unsigned short* __restrict__ mem,
        const int* __restrict__ degs, const unsigned long long* __restrict__ ebits,
        const float* __restrict__ e1, const float* __restrict__ Xs,
        const float* __restrict__ qvec, float* __restrict__ edge, float* __restrict__ q) {
    int gw = (blockIdx.x * blockDim.x + threadIdx.x) >> 6;   // b*CE + e
    int lane = threadIdx.x & 63;
    int b = gw >> 9;
    const float* e1b = e1 + b * CN;
    const float* Xb = Xs + (size_t)b * CN * CD;
    int deg = degs[gw];
    float a0 = 0.f, a1 = 0.f, a2 = 0.f, a3 = 0.f, a4 = 0.f;
    float den = 0.f;
    bool tail = lane < (CD - 256);
    if (deg <= MCAP) {
        const unsigned short* lst = mem + (size_t)gw * MCAP;
        int i = 0;
        for (; i + 4 <= deg; i += 4) {
            ushort4 nn = *reinterpret_cast<const ushort4*>(lst + i);
            float w0 = e1b[nn.x], w1 = e1b[nn.y], w2 = e1b[nn.z], w3 = e1b[nn.w];
            const float* r0 = Xb + (size_t)nn.x * CD;
            const float* r1 = Xb + (size_t)nn.y * CD;
            const float* r2 = Xb + (size_t)nn.z * CD;
            const float* r3 = Xb + (size_t)nn.w * CD;
            float v00 = r0[lane], v01 = r0[lane + 64], v02 = r0[lane + 128], v03 = r0[lane + 192];
            float v10 = r1[lane], v11 = r1[lane + 64], v12 = r1[lane + 128], v13 = r1[lane + 192];
            float v20 = r2[lane], v21 = r2[lane + 64], v22 = r2[lane + 128], v23 = r2[lane + 192];
            float v30 = r3[lane], v31 = r3[lane + 64], v32 = r3[lane + 128], v33 = r3[lane + 192];
            float v04 = 0.f, v14 = 0.f, v24 = 0.f, v34 = 0.f;
            if (tail) { v04 = r0[lane + 256]; v14 = r1[lane + 256]; v24 = r2[lane + 256]; v34 = r3[lane + 256]; }
            den += w0; den += w1; den += w2; den += w3;
            a0 += w0 * v00; a0 += w1 * v10; a0 += w2 * v20; a0 += w3 * v30;
            a1 += w0 * v01; a1 += w1 * v11; a1 += w2 * v21; a1 += w3 * v31;
            a2 += w0 * v02; a2 += w1 * v12; a2 += w2 * v22; a2 += w3 * v32;
            a3 += w0 * v03; a3 += w1 * v13; a3 += w2 * v23; a3 += w3 * v33;
            a4 += w0 * v04; a4 += w1 * v14; a4 += w2 * v24; a4 += w3 * v34;
        }
        for (; i < deg; ++i) {
            int n = lst[i];
            float w = e1b[n];
            const float* r = Xb + (size_t)n * CD;
            den += w;
            a0 += w * r[lane];
            a1 += w * r[lane + 64];
            a2 += w * r[lane + 128];
            a3 += w * r[lane + 192];
            if (tail) a4 += w * r[lane + 256];
        }
    } else {   // overflow fallback (P~1e-20): ebits/ballot path
        const unsigned long long* eb = ebits + (size_t)gw * 16;
#pragma unroll
        for (int c = 0; c < 16; ++c) {
            int n0 = c << 6;
            float wv = e1b[n0 + lane];
            unsigned long long bal = eb[c];
            while (bal) {
                int jj = (int)__ffsll(bal) - 1;
                bal &= bal - 1ull;
                float w = __shfl(wv, jj);
                const float* row = Xb + (size_t)(n0 + jj) * CD;
                den += w;
                a0 += w * row[lane];
                a1 += w * row[lane + 64];
                a2 += w * row[lane + 128];
                a3 += w * row[lane + 192];
                if (tail) a4 += w * row[lane + 256];
            }
        }
    }
    float inv = deg > 0 ? 1.f / den : 0.f;
    float o0 = a0 * inv, o1 = a1 * inv, o2 = a2 * inv, o3 = a3 * inv;
    float o4 = tail ? a4 * inv : 0.f;
    float* erow = edge + (size_t)gw * EP;
    erow[lane]       = o0;
    erow[lane + 64]  = o1;
    erow[lane + 128] = o2;
    erow[lane + 192] = o3;
    erow[lane + 256] = o4;
    float d2 = o0 * qvec[lane];
    d2 += o1 * qvec[lane + 64];
    d2 += o2 * qvec[lane + 128];
    d2 += o3 * qvec[lane + 192];
    if (tail) d2 += o4 * qvec[lane + 256];
    for (int o = 32; o; o >>= 1) d2 += __shfl_down(d2, o);
    if (lane == 0) q[gw] = d2;
}

// ---------- fused node attention v7: one wave per node, no barriers ----------
// Wave computes its node's masked softmax in registers, parks the 512 weights in
// a private LDS row (stride-1 write, broadcast read), then runs a counted unroll-4
// loop over the node's CSR edge list: 1 LDS weight + 2 float4 row loads + 8 FMA.
// cnt==0 -> uniform 1/512 over ALL edges (ascending, matches jax); deg>NCAP ->
// full-e loop with masked weights (w=0 terms add +0.0f, bitwise-neutral).
__global__ __launch_bounds__(512, 8) void k_node_attn(
        const unsigned long long* __restrict__ nbits,
        const unsigned short* __restrict__ nmem, const int* __restrict__ ndegs,
        const float* __restrict__ p, const float* __restrict__ q,
        const float* __restrict__ edge, float alpha, int do_elu,
        float* __restrict__ out) {
    __shared__ float ws[8][CE];                 // per-wave private weight row
    int wv = threadIdx.x >> 6, lane = threadIdx.x & 63;
    int node = blockIdx.x * 8 + wv;             // global node id = b*CN + n
    int b = node >> 10;
    const float* qb = q + (size_t)b * CE;
    const unsigned long long* nb = nbits + (size_t)node * 8;

    // phase 1: masked softmax weights for this node (in-register)
    float pn = p[node];
    float sc[8];
    int cnt = 0;
    float mx = -3.4e38f;
#pragma unroll
    for (int j = 0; j < 8; ++j) {
        int m = (int)((nb[j] >> lane) & 1ull);
        float v = pn + qb[(j << 6) + lane];
        v = v > 0.f ? v : alpha * v;
        v = m ? v : -3.0e38f;
        sc[j] = v;
        cnt += m;
        mx = fmaxf(mx, v);
    }
    for (int o = 32; o; o >>= 1) {
        mx = fmaxf(mx, __shfl_xor(mx, o));
        cnt += __shfl_xor(cnt, o);
    }
    float s = 0.f;
#pragma unroll
    for (int j = 0; j < 8; ++j) { float w = __expf(sc[j] - mx); sc[j] = w; s += w; }
    for (int o = 32; o; o >>= 1) s += __shfl_xor(s, o);
    float scale = cnt > 0 ? 1.f / s : 1.f;
#pragma unroll
    for (int j = 0; j < 8; ++j) {
        int m = (int)((nb[j] >> lane) & 1ull);
        ws[wv][(j << 6) + lane] = m ? sc[j] * scale : 0.f;
    }
    // no __syncthreads: ws row is private to this wave; intra-wave LDS order holds.

    // phase 2: gather-accumulate over this node's edges
    const float4* eb4 = reinterpret_cast<const float4*>(edge + (size_t)b * CE * EP);
    bool two = lane < 11;                       // slots 64..74 handled by lanes 0..10
    float4 acc0 = {0.f, 0.f, 0.f, 0.f}, acc1 = {0.f, 0.f, 0.f, 0.f};
    int deg = ndegs[node];
    if (cnt > 0 && deg <= NCAP) {
        const unsigned short* lst = nmem + (size_t)node * NCAP;
        int i = 0;
        for (; i + 4 <= deg; i += 4) {
            ushort4 ee = *reinterpret_cast<const ushort4*>(lst + i);
            float w0 = ws[wv][ee.x], w1 = ws[wv][ee.y];
            float w2 = ws[wv][ee.z], w3 = ws[wv][ee.w];
            const float4* r0 = eb4 + (size_t)ee.x * 80;
            const float4* r1 = eb4 + (size_t)ee.y * 80;
            const float4* r2 = eb4 + (size_t)ee.z * 80;
            const float4* r3 = eb4 + (size_t)ee.w * 80;
            float4 v0 = r0[lane], v1 = r1[lane], v2 = r2[lane], v3 = r3[lane];
            float4 u0, u1, u2, u3;
            if (two) { u0 = r0[64 + lane]; u1 = r1[64 + lane]; u2 = r2[64 + lane]; u3 = r3[64 + lane]; }
            acc0.x += w0 * v0.x; acc0.y += w0 * v0.y; acc0.z += w0 * v0.z; acc0.w += w0 * v0.w;
            acc0.x += w1 * v1.x; acc0.y += w1 * v1.y; acc0.z += w1 * v1.z; acc0.w += w1 * v1.w;
            acc0.x += w2 * v2.x; acc0.y += w2 * v2.y; acc0.z += w2 * v2.z; acc0.w += w2 * v2.w;
            acc0.x += w3 * v3.x; acc0.y += w3 * v3.y; acc0.z += w3 * v3.z; acc0.w += w3 * v3.w;
            if (two) {
                acc1.x += w0 * u0.x; acc1.y += w0 * u0.y; acc1.z += w0 * u0.z; acc1.w += w0 * u0.w;
                acc1.x += w1 * u1.x; acc1.y += w1 * u1.y; acc1.z += w1 * u1.z; acc1.w += w1 * u1.w;
                acc1.x += w2 * u2.x; acc1.y += w2 * u2.y; acc1.z += w2 * u2.z; acc1.w += w2 * u2.w;
                acc1.x += w3 * u3.x; acc1.y += w3 * u3.y; acc1.z += w3 * u3.z; acc1.w += w3 * u3.w;
            }
        }
        for (; i < deg; ++i) {
            int e = lst[i];
            float w = ws[wv][e];
            const float4* r = eb4 + (size_t)e * 80;
            float4 v = r[lane];
            acc0.x += w * v.x; acc0.y += w * v.y; acc0.z += w * v.z; acc0.w += w * v.w;
            if (two) {
                float4 u = r[64 + lane];
                acc1.x += w * u.x; acc1.y += w * u.y; acc1.z += w * u.z; acc1.w += w * u.w;
            }
        }
    } else {
        // cnt==0: uniform softmax over all 512 edges (jax all-NEG row behavior).
        // deg>NCAP overflow: full loop with masked weights (zeros are +0.0 no-ops).
        float uw = 1.f / (float)CE;
        for (int e = 0; e < CE; ++e) {
            float w = cnt > 0 ? ws[wv][e] : uw;
            const float4* r = eb4 + (size_t)e * 80;
            float4 v = r[lane];
            acc0.x += w * v.x; acc0.y += w * v.y; acc0.z += w * v.z; acc0.w += w * v.w;
            if (two) {
                float4 u = r[64 + lane];
                acc1.x += w * u.x; acc1.y += w * u.y; acc1.z += w * u.z; acc1.w += w * u.w;
            }
        }
    }
    if (do_elu) {
        acc0.x = acc0.x > 0.f ? acc0.x : expm1f(acc0.x);
        acc0.y = acc0.y > 0.f ? acc0.y : expm1f(acc0.y);
        acc0.z = acc0.z > 0.f ? acc0.z : expm1f(acc0.z);
        acc0.w = acc0.w > 0.f ? acc0.w : expm1f(acc0.w);
        acc1.x = acc1.x > 0.f ? acc1.x : expm1f(acc1.x);
        acc1.y = acc1.y > 0.f ? acc1.y : expm1f(acc1.y);
        acc1.z = acc1.z > 0.f ? acc1.z : expm1f(acc1.z);
        acc1.w = acc1.w > 0.f ? acc1.w : expm1f(acc1.w);
    }
    float* orow = out + (size_t)node * CD;
    *reinterpret_cast<float4*>(orow + (lane << 2)) = acc0;       // slots 0..63
    if (two) *reinterpret_cast<float4*>(orow + ((64 + lane) << 2)) = acc1;  // 64..74
}

extern "C" void kernel_launch(void* const* d_in, const int* in_sizes, int n_in,
                              void* d_out, int out_size, void* d_ws, size_t ws_size,
                              hipStream_t stream) {
    const int*   inputs = (const int*)d_in[0];
    const int*   HT     = (const int*)d_in[1];
    const float* emb    = (const float*)d_in[2];
    const float* w2_1   = (const float*)d_in[3];
    const float* w3_1   = (const float*)d_in[4];
    const float* a_1    = (const float*)d_in[5];
    const float* a2_1   = (const float*)d_in[6];
    const float* wc_1   = (const float*)d_in[7];
    const float* w_2    = (const float*)d_in[8];
    const float* w2_2   = (const float*)d_in[9];
    const float* w3_2   = (const float*)d_in[10];
    const float* a_2    = (const float*)d_in[11];
    const float* a2_2   = (const float*)d_in[12];
    const float* wc_2   = (const float*)d_in[13];

    char* ws = (char*)d_ws;
    float* big0               = (float*)(ws);                          // 39,321,600 B: X0 -> X1
    float* big1               = (float*)(ws + 39321600);               // 39,321,600 B: XW
    float* edge               = (float*)(ws + 78643200);               // 20,971,520 B (EP=320)
    unsigned long long* ebits = (unsigned long long*)(ws + 99614720);  //  2,097,152 B
    unsigned long long* nbits = (unsigned long long*)(ws + 101711872); //  2,097,152 B
    unsigned short* mem       = (unsigned short*)(ws + 103809024);     //  6,291,456 B
    unsigned short* nmem      = (unsigned short*)(ws + 110100480);     //  6,291,456 B
    int* degs                 = (int*)(ws + 116391936);                //     65,536 B
    int* ndegs                = (int*)(ws + 116457472);                //    131,072 B
    float* s1                 = (float*)(ws + 116588544);              //    131,072 B
    float* p                  = (float*)(ws + 116719616);              //    131,072 B
    float* e1                 = (float*)(ws + 116850688);              //    131,072 B
    float* qv                 = (float*)(ws + 116981760);              //     65,536 B
    float* vecs               = (float*)(ws + 117047296);              //      7,200 B
    // total: 117,054,496 B

    k_embed<<<9600, 256, 0, stream>>>(inputs, emb, big0);
    k_ebits<<<4096, 256, 0, stream>>>(HT, ebits);
    k_bitT<<<512, 512, 0, stream>>>(ebits, nbits);
    k_members<<<4096, 256, 0, stream>>>(ebits, mem, degs);
    k_nmem<<<8192, 256, 0, stream>>>(nbits, nmem, ndegs);
    k_prep<<<6, 320, 0, stream>>>(w2_1, w3_1, a_1, a2_1, w2_2, w3_2, a_2, a2_2, vecs);

    // ---- layer 1: transfer=False, concat=True (ELU), alpha=0.1 ----
    k_score<<<CB * CN / 4, 256, 0, stream>>>(big0, vecs, vecs + CD, wc_1, a_1, 0.1f, s1, p, CB * CN);
    k_bmax<<<CB, 1024, 0, stream>>>(s1, e1);
    k_edge_agg<<<4096, 256, 0, stream>>>(mem, degs, ebits, e1, big0, vecs + 2 * CD, edge, qv);
    k_node_attn<<<4096, 512, 0, stream>>>(nbits, nmem, ndegs, p, qv, edge, 0.1f, 1, big0);  // X1

    // ---- layer 2: transfer=True, concat=False, alpha=0.2 ----
    k_score<<<CB * CN / 4, 256, 0, stream>>>(big0, vecs + 3 * CD, vecs + 4 * CD, wc_2, a_2, 0.2f, s1, p, CB * CN);
    k_gemm300<<<dim3(5, 512), 256, 0, stream>>>(big0, w_2, big1, CB * CN, CD, CD);   // XW = X1 @ w_2
    k_bmax<<<CB, 1024, 0, stream>>>(s1, e1);
    k_edge_agg<<<4096, 256, 0, stream>>>(mem, degs, ebits, e1, big1, vecs + 5 * CD, edge, qv);
    k_node_attn<<<4096, 512, 0, stream>>>(nbits, nmem, ndegs, p, qv, edge, 0.2f, 0, (float*)d_out);
}

// Round 11
// 688.820 us; speedup vs baseline: 1.0227x; 1.0227x over previous
//
#include <hip/hip_runtime.h>
#include <hip/hip_bf16.h>

#define CB 32
#define CN 1024
#define CE 512
#define CD 300
#define EP 320    // padded edge-row stride (floats); pad cols [300,320) are written 0
#define UCAP 320  // union-list capacity per 4-node group (mean 176, sd ~11)
#define MCAP 192  // member-list capacity per edge (deg ~ B(1024,.1): mean 102, sd 9.6)

// ---------- embedding gather: X[r,:] = emb[idx[r],:] ----------
__global__ void k_embed(const int* __restrict__ idx, const float* __restrict__ emb,
                        float* __restrict__ X) {
    int gid = blockIdx.x * blockDim.x + threadIdx.x;
    const int total = CB * CN * 75;
    if (gid >= total) return;
    int r = gid / 75, c = gid % 75;
    int e = idx[r];
    reinterpret_cast<float4*>(X)[(size_t)r * 75 + c] =
        reinterpret_cast<const float4*>(emb)[(size_t)e * 75 + c];
}

// ---------- ebits[b*E+e][c] = ballot(HT[b,e,c*64+lane] != 0) ----------
__global__ void k_ebits(const int* __restrict__ HT, unsigned long long* __restrict__ ebits) {
    int gw = (blockIdx.x * blockDim.x + threadIdx.x) >> 6;   // b*CE+e
    int lane = threadIdx.x & 63;
    const int* hrow = HT + (size_t)gw * CN;
#pragma unroll
    for (int c = 0; c < 16; ++c) {
        unsigned long long bal = __ballot(hrow[(c << 6) + lane] != 0);
        if (lane == 0) ebits[(size_t)gw * 16 + c] = bal;
    }
}

// ---------- nbits = bit-transpose of ebits ----------
__global__ __launch_bounds__(512) void k_bitT(const unsigned long long* __restrict__ ebits,
        unsigned long long* __restrict__ nbits) {
    __shared__ unsigned long long w[8][64];
    int b = blockIdx.x >> 4, nc = blockIdx.x & 15;
    int tid = threadIdx.x, ec = tid >> 6, lane = tid & 63;
    w[ec][lane] = ebits[((size_t)b * CE + (ec << 6) + lane) * 16 + nc];
    __syncthreads();
    unsigned long long out = 0;
#pragma unroll
    for (int j = 0; j < 64; ++j)
        out |= ((w[ec][j] >> lane) & 1ull) << j;
    nbits[((size_t)b * CN + (nc << 6) + lane) * 8 + ec] = out;
}

// ---------- member lists: mem[gw][0..deg) = ascending node ids of edge gw ----------
__global__ void k_members(const unsigned long long* __restrict__ ebits,
                          unsigned short* __restrict__ mem, int* __restrict__ degs) {
    int gw = (blockIdx.x * blockDim.x + threadIdx.x) >> 6;
    int lane = threadIdx.x & 63;
    const unsigned long long* eb = ebits + (size_t)gw * 16;
    unsigned short* lst = mem + (size_t)gw * MCAP;
    int base = 0;
    unsigned long long lmask = (1ull << lane) - 1ull;
#pragma unroll
    for (int c = 0; c < 16; ++c) {
        unsigned long long w = eb[c];
        if ((w >> lane) & 1ull) {
            int off = base + (int)__popcll(w & lmask);
            if (off < MCAP) lst[off] = (unsigned short)((c << 6) + lane);
        }
        base += (int)__popcll(w);
    }
    if (lane == 0) degs[gw] = base;   // may exceed MCAP -> fallback path
}

// ---------- k_prep: vecs = 6 folded attention vectors ----------
__global__ void k_prep(const float* __restrict__ w2_1, const float* __restrict__ w3_1,
                       const float* __restrict__ a_1, const float* __restrict__ a2_1,
                       const float* __restrict__ w2_2, const float* __restrict__ w3_2,
                       const float* __restrict__ a_2, const float* __restrict__ a2_2,
                       float* __restrict__ vecs) {
    int which = blockIdx.x;
    int t = threadIdx.x;
    if (t >= CD) return;
    const float* W; const float* v;
    switch (which) {
        case 0:  W = w2_1; v = a_1 + CD;  break;
        case 1:  W = w2_1; v = a2_1;      break;
        case 2:  W = w3_1; v = a2_1 + CD; break;
        case 3:  W = w2_2; v = a_2 + CD;  break;
        case 4:  W = w2_2; v = a2_2;      break;
        default: W = w3_2; v = a2_2 + CD; break;
    }
    float s = 0.f;
    for (int j = 0; j < CD; ++j) s += W[(size_t)t * CD + j] * v[j];
    vecs[which * CD + t] = s;
}

// ---------- C[M,300] = A[M,300(lda)] @ W[300,300] ----------
__global__ __launch_bounds__(256) void k_gemm300(const float* __restrict__ A,
                                                 const float* __restrict__ W,
                                                 float* __restrict__ C, int M,
                                                 int lda, int ldc) {
    __shared__ float As[64][20];
    __shared__ float Ws[16][68];
    int tid = threadIdx.x;
    int n0 = blockIdx.x * 64, m0 = blockIdx.y * 64;
    int tx = tid & 15, ty = tid >> 4;
    int la_r = tid >> 2, la_c = (tid & 3) << 2;
    int lw_r = tid >> 4, lw_c = (tid & 15) << 2;
    float acc[4][4] = {};
    for (int k0 = 0; k0 < CD; k0 += 16) {
        {
            int kc = k0 + la_c;
            const float* Ap = A + (size_t)(m0 + la_r) * lda + kc;
            float4 av;
            if (kc + 3 < CD) av = *reinterpret_cast<const float4*>(Ap);
            else {
                av.x = kc     < CD ? Ap[0] : 0.f;
                av.y = kc + 1 < CD ? Ap[1] : 0.f;
                av.z = kc + 2 < CD ? Ap[2] : 0.f;
                av.w = 0.f;
            }
            *reinterpret_cast<float4*>(&As[la_r][la_c]) = av;
        }
        {
            int kr = k0 + lw_r;
            float4 wv = {0.f, 0.f, 0.f, 0.f};
            if (kr < CD) {
                const float* Wp = W + (size_t)kr * CD + n0 + lw_c;
                if (n0 + lw_c + 3 < CD) wv = *reinterpret_cast<const float4*>(Wp);
                else {
                    if (n0 + lw_c     < CD) wv.x = Wp[0];
                    if (n0 + lw_c + 1 < CD) wv.y = Wp[1];
                    if (n0 + lw_c + 2 < CD) wv.z = Wp[2];
                }
            }
            *reinterpret_cast<float4*>(&Ws[lw_r][lw_c]) = wv;
        }
        __syncthreads();
#pragma unroll
        for (int k = 0; k < 16; ++k) {
            float av[4];
#pragma unroll
            for (int i = 0; i < 4; ++i) av[i] = As[ty * 4 + i][k];
            float4 bv = *reinterpret_cast<const float4*>(&Ws[k][tx * 4]);
            float bb[4] = {bv.x, bv.y, bv.z, bv.w};
#pragma unroll
            for (int i = 0; i < 4; ++i)
#pragma unroll
                for (int j = 0; j < 4; ++j) acc[i][j] += av[i] * bb[j];
        }
        __syncthreads();
    }
    for (int i = 0; i < 4; ++i) {
        int m = m0 + ty * 4 + i;
        int n = n0 + tx * 4;
        float* Cp = C + (size_t)m * ldc + n;
        if (n + 3 < CD) {
            float4 v = {acc[i][0], acc[i][1], acc[i][2], acc[i][3]};
            *reinterpret_cast<float4*>(Cp) = v;
        } else {
            for (int j = 0; j < 4; ++j) if (n + j < CD) Cp[j] = acc[i][j];
        }
    }
}

// ---------- s1[r] = leaky(wc·a_top + X[r,:]·av), p[r] = X[r,:]·pv ----------
__global__ void k_score(const float* __restrict__ X, const float* __restrict__ av,
                        const float* __restrict__ pv, const float* __restrict__ wc,
                        const float* __restrict__ a_orig,
                        float alpha, float* __restrict__ s1, float* __restrict__ p, int M) {
    int gw = (blockIdx.x * blockDim.x + threadIdx.x) >> 6;
    int lane = threadIdx.x & 63;
    if (gw >= M) return;
    const float* row = X + (size_t)gw * CD;
    float d1 = 0.f, d2 = 0.f, dc = 0.f;
    for (int d = lane; d < CD; d += 64) {
        float x = row[d];
        d1 += x * av[d];
        d2 += x * pv[d];
        dc += wc[d] * a_orig[d];
    }
    for (int o = 32; o; o >>= 1) {
        d1 += __shfl_down(d1, o);
        d2 += __shfl_down(d2, o);
        dc += __shfl_down(dc, o);
    }
    if (lane == 0) {
        float v = dc + d1;
        s1[gw] = v > 0.f ? v : alpha * v;
        p[gw] = d2;
    }
}

// ---------- per-batch max over s1, e1 = exp(s1 - max) ----------
__global__ __launch_bounds__(1024) void k_bmax(const float* __restrict__ s1,
                                               float* __restrict__ e1) {
    __shared__ float red[16];
    int b = blockIdx.x, t = threadIdx.x;
    float v = s1[b * CN + t];
    float m = v;
    for (int o = 32; o; o >>= 1) m = fmaxf(m, __shfl_xor(m, o));
    if ((t & 63) == 0) red[t >> 6] = m;
    __syncthreads();
    if (t == 0) {
        float mm = red[0];
        for (int i = 1; i < 16; ++i) mm = fmaxf(mm, red[i]);
        red[0] = mm;
    }
    __syncthreads();
    e1[b * CN + t] = __expf(v - red[0]);
}

// ---------- sparse edge aggregation + fused q (CSR list, float4 slots, unroll-4) ----------
// One wave per (b,e). Lane owns f4 dim-slots {lane} (floats 0..255) and
// {64+lane | lane<11} (floats 256..299); lanes 11..15 zero the pad slots 75..79.
// Counted loop over ascending member list: per 4 members, 4 weight loads +
// 8 float4 row loads (vs 24 scalar VMEM in R8). Per-dim member summation order
// identical to R8 -> edge values unchanged.
__global__ __launch_bounds__(256) void k_edge_agg(const unsigned short* __restrict__ mem,
        const int* __restrict__ degs, const unsigned long long* __restrict__ ebits,
        const float* __restrict__ e1, const float* __restrict__ Xs,
        const float* __restrict__ qvec, float* __restrict__ edge, float* __restrict__ q) {
    int gw = (blockIdx.x * blockDim.x + threadIdx.x) >> 6;   // b*CE + e
    int lane = threadIdx.x & 63;
    int b = gw >> 9;
    const float* e1b = e1 + b * CN;
    int deg = degs[gw];
    float* erow = edge + (size_t)gw * EP;

    if (deg > MCAP) {   // overflow fallback (P~1e-20): R8-proven scalar ballot path
        const float* Xb = Xs + (size_t)b * CN * CD;
        const unsigned long long* eb = ebits + (size_t)gw * 16;
        float a0 = 0.f, a1 = 0.f, a2 = 0.f, a3 = 0.f, a4 = 0.f;
        float den = 0.f;
        bool tail = lane < (CD - 256);
#pragma unroll
        for (int c = 0; c < 16; ++c) {
            int n0 = c << 6;
            float wv = e1b[n0 + lane];
            unsigned long long bal = eb[c];
            while (bal) {
                int jj = (int)__ffsll(bal) - 1;
                bal &= bal - 1ull;
                float w = __shfl(wv, jj);
                const float* row = Xb + (size_t)(n0 + jj) * CD;
                den += w;
                a0 += w * row[lane];
                a1 += w * row[lane + 64];
                a2 += w * row[lane + 128];
                a3 += w * row[lane + 192];
                if (tail) a4 += w * row[lane + 256];
            }
        }
        float inv = deg > 0 ? 1.f / den : 0.f;
        float o0 = a0 * inv, o1 = a1 * inv, o2 = a2 * inv, o3 = a3 * inv;
        float o4 = tail ? a4 * inv : 0.f;
        erow[lane]       = o0;
        erow[lane + 64]  = o1;
        erow[lane + 128] = o2;
        erow[lane + 192] = o3;
        erow[lane + 256] = o4;
        float d2 = o0 * qvec[lane];
        d2 += o1 * qvec[lane + 64];
        d2 += o2 * qvec[lane + 128];
        d2 += o3 * qvec[lane + 192];
        if (tail) d2 += o4 * qvec[lane + 256];
        for (int o = 32; o; o >>= 1) d2 += __shfl_down(d2, o);
        if (lane == 0) q[gw] = d2;
        return;
    }

    const float4* Xb4 = reinterpret_cast<const float4*>(Xs + (size_t)b * CN * CD);
    const unsigned short* lst = mem + (size_t)gw * MCAP;
    bool two = lane < 11;   // 75 f4 slots per row: 64..74 handled by lanes 0..10
    float4 a0 = {0.f, 0.f, 0.f, 0.f}, a1 = {0.f, 0.f, 0.f, 0.f};
    float den = 0.f;
    int i = 0;
    for (; i + 4 <= deg; i += 4) {
        ushort4 nn = *reinterpret_cast<const ushort4*>(lst + i);
        float w0 = e1b[nn.x], w1 = e1b[nn.y], w2 = e1b[nn.z], w3 = e1b[nn.w];
        const float4* r0 = Xb4 + (size_t)nn.x * 75;
        const float4* r1 = Xb4 + (size_t)nn.y * 75;
        const float4* r2 = Xb4 + (size_t)nn.z * 75;
        const float4* r3 = Xb4 + (size_t)nn.w * 75;
        float4 v0 = r0[lane], v1 = r1[lane], v2 = r2[lane], v3 = r3[lane];
        float4 u0, u1, u2, u3;
        if (two) { u0 = r0[64 + lane]; u1 = r1[64 + lane]; u2 = r2[64 + lane]; u3 = r3[64 + lane]; }
        den += w0; den += w1; den += w2; den += w3;
        a0.x += w0 * v0.x; a0.y += w0 * v0.y; a0.z += w0 * v0.z; a0.w += w0 * v0.w;
        a0.x += w1 * v1.x; a0.y += w1 * v1.y; a0.z += w1 * v1.z; a0.w += w1 * v1.w;
        a0.x += w2 * v2.x; a0.y += w2 * v2.y; a0.z += w2 * v2.z; a0.w += w2 * v2.w;
        a0.x += w3 * v3.x; a0.y += w3 * v3.y; a0.z += w3 * v3.z; a0.w += w3 * v3.w;
        if (two) {
            a1.x += w0 * u0.x; a1.y += w0 * u0.y; a1.z += w0 * u0.z; a1.w += w0 * u0.w;
            a1.x += w1 * u1.x; a1.y += w1 * u1.y; a1.z += w1 * u1.z; a1.w += w1 * u1.w;
            a1.x += w2 * u2.x; a1.y += w2 * u2.y; a1.z += w2 * u2.z; a1.w += w2 * u2.w;
            a1.x += w3 * u3.x; a1.y += w3 * u3.y; a1.z += w3 * u3.z; a1.w += w3 * u3.w;
        }
    }
    for (; i < deg; ++i) {
        int n = lst[i];
        float w = e1b[n];
        const float4* r = Xb4 + (size_t)n * 75;
        float4 v = r[lane];
        den += w;
        a0.x += w * v.x; a0.y += w * v.y; a0.z += w * v.z; a0.w += w * v.w;
        if (two) {
            float4 u = r[64 + lane];
            a1.x += w * u.x; a1.y += w * u.y; a1.z += w * u.z; a1.w += w * u.w;
        }
    }
    float inv = deg > 0 ? 1.f / den : 0.f;
    float4 o0 = {a0.x * inv, a0.y * inv, a0.z * inv, a0.w * inv};
    float4 o1 = {a1.x * inv, a1.y * inv, a1.z * inv, a1.w * inv};
    float4* er4 = reinterpret_cast<float4*>(erow);
    er4[lane] = o0;
    if (two) er4[64 + lane] = o1;
    else if (lane < 16) er4[64 + lane] = make_float4(0.f, 0.f, 0.f, 0.f);  // pad 75..79
    // fused q = edge_row · qvec
    const float4* qv4 = reinterpret_cast<const float4*>(qvec);
    float4 qa = qv4[lane];
    float d2 = o0.x * qa.x + o0.y * qa.y + o0.z * qa.z + o0.w * qa.w;
    if (two) {
        float4 qb2 = qv4[64 + lane];
        d2 += o1.x * qb2.x + o1.y * qb2.y + o1.z * qb2.z + o1.w * qb2.w;
    }
    for (int o = 32; o; o >>= 1) d2 += __shfl_down(d2, o);
    if (lane == 0) q[gw] = d2;
}

// ---------- fused node attention (R8-proven): nbits masks + compacted weights ----------
#define ACC16(vv, ww) do { \
    acc[0][0] += (ww).x * (vv).x; acc[0][1] += (ww).x * (vv).y; \
    acc[0][2] += (ww).x * (vv).z; acc[0][3] += (ww).x * (vv).w; \
    acc[1][0] += (ww).y * (vv).x; acc[1][1] += (ww).y * (vv).y; \
    acc[1][2] += (ww).y * (vv).z; acc[1][3] += (ww).y * (vv).w; \
    acc[2][0] += (ww).z * (vv).x; acc[2][1] += (ww).z * (vv).y; \
    acc[2][2] += (ww).z * (vv).z; acc[2][3] += (ww).z * (vv).w; \
    acc[3][0] += (ww).w * (vv).x; acc[3][1] += (ww).w * (vv).y; \
    acc[3][2] += (ww).w * (vv).z; acc[3][3] += (ww).w * (vv).w; \
} while (0)

__global__ __launch_bounds__(320) void k_node_attn(const unsigned long long* __restrict__ nbits,
        const float* __restrict__ p, const float* __restrict__ q,
        const float* __restrict__ edge, float alpha, int do_elu, float* __restrict__ out) {
    __shared__ float4 wsc[4][UCAP];
    __shared__ __align__(8) unsigned short ul[4][UCAP];
    __shared__ int ucnt_s[4], flag_s[4];
    __shared__ float gpn[16], gmx[16], gsc[16];
    __shared__ int gct[16];
    int blk = blockIdx.x;
    int b = blk >> 6, n0 = (blk & 63) << 4;
    int tid = threadIdx.x, wv = tid >> 6, lane = tid & 63;
    const float* qb = q + b * CE;

    if (wv < 4) {
        float pn[4]; const unsigned long long* nb[4];
#pragma unroll
        for (int k = 0; k < 4; ++k) {
            int n = n0 + 4 * wv + k;
            pn[k] = p[b * CN + n];
            nb[k] = nbits + ((size_t)b * CN + n) * 8;
        }
        float sc[4][8];
        int cnt[4] = {0, 0, 0, 0};
        float mx[4] = {-3.4e38f, -3.4e38f, -3.4e38f, -3.4e38f};
        int ubits = 0;
#pragma unroll
        for (int j = 0; j < 8; ++j) {
            int e = lane + (j << 6);
            float qe = qb[e];
            int many = 0;
#pragma unroll
            for (int k = 0; k < 4; ++k) {
                int m = (int)((nb[k][j] >> lane) & 1ull);
                float v = pn[k] + qe;
                v = v > 0.f ? v : alpha * v;
                v = m ? v : -3.0e38f;
                cnt[k] += m; many |= m;
                mx[k] = fmaxf(mx[k], v);
                sc[k][j] = v;
            }
            ubits |= (many ? 1 : 0) << j;
        }
#pragma unroll
        for (int k = 0; k < 4; ++k) {
            for (int o = 32; o; o >>= 1) {
                mx[k] = fmaxf(mx[k], __shfl_xor(mx[k], o));
                cnt[k] += __shfl_xor(cnt[k], o);
            }
        }
        float scale[4];
#pragma unroll
        for (int k = 0; k < 4; ++k) {
            float s = 0.f;
#pragma unroll
            for (int j = 0; j < 8; ++j) { float w8 = __expf(sc[k][j] - mx[k]); sc[k][j] = w8; s += w8; }
            for (int o = 32; o; o >>= 1) s += __shfl_xor(s, o);
            scale[k] = cnt[k] > 0 ? 1.f / s : 1.f;
        }
        int base = 0;
        unsigned long long lmask = (1ull << lane) - 1ull;
#pragma unroll
        for (int j = 0; j < 8; ++j) {
            unsigned long long bal = __ballot((ubits >> j) & 1);
            if ((ubits >> j) & 1) {
                int off = base + (int)__popcll(bal & lmask);
                if (off < UCAP) {
                    ul[wv][off] = (unsigned short)(lane + (j << 6));
                    wsc[wv][off] = make_float4(sc[0][j] * scale[0], sc[1][j] * scale[1],
                                               sc[2][j] * scale[2], sc[3][j] * scale[3]);
                }
            }
            base += (int)__popcll(bal);
        }
        if (lane == 0) {
            ucnt_s[wv] = base < UCAP ? base : UCAP;
            flag_s[wv] = (cnt[0] == 0) | (cnt[1] == 0) | (cnt[2] == 0) | (cnt[3] == 0) |
                         (base > UCAP);
            gpn[wv*4+0]=pn[0]; gmx[wv*4+0]=mx[0]; gsc[wv*4+0]=scale[0]; gct[wv*4+0]=cnt[0];
            gpn[wv*4+1]=pn[1]; gmx[wv*4+1]=mx[1]; gsc[wv*4+1]=scale[1]; gct[wv*4+1]=cnt[1];
            gpn[wv*4+2]=pn[2]; gmx[wv*4+2]=mx[2]; gsc[wv*4+2]=scale[2]; gct[wv*4+2]=cnt[2];
            gpn[wv*4+3]=pn[3]; gmx[wv*4+3]=mx[3]; gsc[wv*4+3]=scale[3]; gct[wv*4+3]=cnt[3];
        }
    }
    __syncthreads();

    int grp = tid / 80;
    int j4 = tid - grp * 80;
    const float4* eb4 = reinterpret_cast<const float4*>(edge + (size_t)b * CE * EP) + j4;
    int cnt = ucnt_s[grp], bad = flag_s[grp];
    float acc[4][4] = {};
    if (!bad) {
        int i = 0;
        for (; i + 8 <= cnt; i += 8) {
            ushort4 ua = *reinterpret_cast<const ushort4*>(&ul[grp][i]);
            ushort4 ub = *reinterpret_cast<const ushort4*>(&ul[grp][i + 4]);
            float4 v0 = eb4[(size_t)ua.x * 80], v1 = eb4[(size_t)ua.y * 80];
            float4 v2 = eb4[(size_t)ua.z * 80], v3 = eb4[(size_t)ua.w * 80];
            float4 v4 = eb4[(size_t)ub.x * 80], v5 = eb4[(size_t)ub.y * 80];
            float4 v6 = eb4[(size_t)ub.z * 80], v7 = eb4[(size_t)ub.w * 80];
            { float4 w = wsc[grp][i];     ACC16(v0, w); }
            { float4 w = wsc[grp][i + 1]; ACC16(v1, w); }
            { float4 w = wsc[grp][i + 2]; ACC16(v2, w); }
            { float4 w = wsc[grp][i + 3]; ACC16(v3, w); }
            { float4 w = wsc[grp][i + 4]; ACC16(v4, w); }
            { float4 w = wsc[grp][i + 5]; ACC16(v5, w); }
            { float4 w = wsc[grp][i + 6]; ACC16(v6, w); }
            { float4 w = wsc[grp][i + 7]; ACC16(v7, w); }
        }
        for (; i < cnt; ++i) {
            int e = ul[grp][i];
            float4 v = eb4[(size_t)e * 80];
            float4 w = wsc[grp][i];
            ACC16(v, w);
        }
    } else {
        float pnk[4], mxk[4], sck[4]; int ctk[4];
        const unsigned long long* nbr[4];
#pragma unroll
        for (int k = 0; k < 4; ++k) {
            pnk[k] = gpn[grp*4+k]; mxk[k] = gmx[grp*4+k]; sck[k] = gsc[grp*4+k]; ctk[k] = gct[grp*4+k];
            nbr[k] = nbits + ((size_t)b * CN + n0 + grp * 4 + k) * 8;
        }
        for (int e = 0; e < CE; ++e) {
            float4 v = eb4[(size_t)e * 80];
            float qe = qb[e];
#pragma unroll
            for (int k = 0; k < 4; ++k) {
                int m = (int)((nbr[k][e >> 6] >> (e & 63)) & 1ull);
                float vv = pnk[k] + qe; vv = vv > 0.f ? vv : alpha * vv;
                float w = ctk[k] == 0 ? (1.f / CE) : (m ? __expf(vv - mxk[k]) * sck[k] : 0.f);
                acc[k][0] += w * v.x; acc[k][1] += w * v.y; acc[k][2] += w * v.z; acc[k][3] += w * v.w;
            }
        }
    }
    if (j4 < 75) {
#pragma unroll
        for (int ni = 0; ni < 4; ++ni) {
            float4 o = {acc[ni][0], acc[ni][1], acc[ni][2], acc[ni][3]};
            if (do_elu) {
                o.x = o.x > 0.f ? o.x : expm1f(o.x);
                o.y = o.y > 0.f ? o.y : expm1f(o.y);
                o.z = o.z > 0.f ? o.z : expm1f(o.z);
                o.w = o.w > 0.f ? o.w : expm1f(o.w);
            }
            *reinterpret_cast<float4*>(out + ((size_t)b * CN + n0 + grp * 4 + ni) * CD + j4 * 4) = o;
        }
    }
}

extern "C" void kernel_launch(void* const* d_in, const int* in_sizes, int n_in,
                              void* d_out, int out_size, void* d_ws, size_t ws_size,
                              hipStream_t stream) {
    const int*   inputs = (const int*)d_in[0];
    const int*   HT     = (const int*)d_in[1];
    const float* emb    = (const float*)d_in[2];
    const float* w2_1   = (const float*)d_in[3];
    const float* w3_1   = (const float*)d_in[4];
    const float* a_1    = (const float*)d_in[5];
    const float* a2_1   = (const float*)d_in[6];
    const float* wc_1   = (const float*)d_in[7];
    const float* w_2    = (const float*)d_in[8];
    const float* w2_2   = (const float*)d_in[9];
    const float* w3_2   = (const float*)d_in[10];
    const float* a_2    = (const float*)d_in[11];
    const float* a2_2   = (const float*)d_in[12];
    const float* wc_2   = (const float*)d_in[13];

    char* ws = (char*)d_ws;
    float* big0               = (float*)(ws);                          // 39,321,600 B: X0 -> X1
    float* big1               = (float*)(ws + 39321600);               // 39,321,600 B: XW
    float* edge               = (float*)(ws + 78643200);               // 20,971,520 B (EP=320)
    unsigned long long* ebits = (unsigned long long*)(ws + 99614720);  //  2,097,152 B
    unsigned long long* nbits = (unsigned long long*)(ws + 101711872); //  2,097,152 B
    unsigned short* mem       = (unsigned short*)(ws + 103809024);     //  6,291,456 B
    int* degs                 = (int*)(ws + 110100480);                //     65,536 B
    float* s1                 = (float*)(ws + 110166016);              //    131,072 B
    float* p                  = (float*)(ws + 110297088);              //    131,072 B
    float* e1                 = (float*)(ws + 110428160);              //    131,072 B
    float* qv                 = (float*)(ws + 110559232);              //     65,536 B
    float* vecs               = (float*)(ws + 110624768);              //      7,200 B
    // total: 110,631,968 B

    k_embed<<<9600, 256, 0, stream>>>(inputs, emb, big0);
    k_ebits<<<4096, 256, 0, stream>>>(HT, ebits);
    k_bitT<<<512, 512, 0, stream>>>(ebits, nbits);
    k_members<<<4096, 256, 0, stream>>>(ebits, mem, degs);
    k_prep<<<6, 320, 0, stream>>>(w2_1, w3_1, a_1, a2_1, w2_2, w3_2, a_2, a2_2, vecs);

    // ---- layer 1: transfer=False, concat=True (ELU), alpha=0.1 ----
    k_score<<<CB * CN / 4, 256, 0, stream>>>(big0, vecs, vecs + CD, wc_1, a_1, 0.1f, s1, p, CB * CN);
    k_bmax<<<CB, 1024, 0, stream>>>(s1, e1);
    k_edge_agg<<<4096, 256, 0, stream>>>(mem, degs, ebits, e1, big0, vecs + 2 * CD, edge, qv);
    k_node_attn<<<2048, 320, 0, stream>>>(nbits, p, qv, edge, 0.1f, 1, big0);   // X1 -> big0

    // ---- layer 2: transfer=True, concat=False, alpha=0.2 ----
    k_score<<<CB * CN / 4, 256, 0, stream>>>(big0, vecs + 3 * CD, vecs + 4 * CD, wc_2, a_2, 0.2f, s1, p, CB * CN);
    k_gemm300<<<dim3(5, 512), 256, 0, stream>>>(big0, w_2, big1, CB * CN, CD, CD);   // XW = X1 @ w_2
    k_bmax<<<CB, 1024, 0, stream>>>(s1, e1);
    k_edge_agg<<<4096, 256, 0, stream>>>(mem, degs, ebits, e1, big1, vecs + 5 * CD, edge, qv);
    k_node_attn<<<2048, 320, 0, stream>>>(nbits, p, qv, edge, 0.2f, 0, (float*)d_out);
}

// Round 12
// 640.922 us; speedup vs baseline: 1.0991x; 1.0747x over previous
//
#include <hip/hip_runtime.h>
#include <hip/hip_bf16.h>

#define CB 32
#define CN 1024
#define CE 512
#define CD 300
#define EP 320    // padded edge-row stride (floats); pad cols [300,320) are written 0
#define UCAP 320  // union-list capacity per 4-node group (mean 176, sd ~11)
#define MCAP 192  // member-list capacity per edge (deg ~ B(1024,.1): mean 102, sd 9.6)

// ---------- embedding gather: X[r,:] = emb[idx[r],:] ----------
__global__ void k_embed(const int* __restrict__ idx, const float* __restrict__ emb,
                        float* __restrict__ X) {
    int gid = blockIdx.x * blockDim.x + threadIdx.x;
    const int total = CB * CN * 75;
    if (gid >= total) return;
    int r = gid / 75, c = gid % 75;
    int e = idx[r];
    reinterpret_cast<float4*>(X)[(size_t)r * 75 + c] =
        reinterpret_cast<const float4*>(emb)[(size_t)e * 75 + c];
}

// ---------- ebits[b*E+e][c] = ballot(HT[b,e,c*64+lane] != 0) ----------
__global__ void k_ebits(const int* __restrict__ HT, unsigned long long* __restrict__ ebits) {
    int gw = (blockIdx.x * blockDim.x + threadIdx.x) >> 6;   // b*CE+e
    int lane = threadIdx.x & 63;
    const int* hrow = HT + (size_t)gw * CN;
#pragma unroll
    for (int c = 0; c < 16; ++c) {
        unsigned long long bal = __ballot(hrow[(c << 6) + lane] != 0);
        if (lane == 0) ebits[(size_t)gw * 16 + c] = bal;
    }
}

// ---------- nbits = bit-transpose of ebits ----------
__global__ __launch_bounds__(512) void k_bitT(const unsigned long long* __restrict__ ebits,
        unsigned long long* __restrict__ nbits) {
    __shared__ unsigned long long w[8][64];
    int b = blockIdx.x >> 4, nc = blockIdx.x & 15;
    int tid = threadIdx.x, ec = tid >> 6, lane = tid & 63;
    w[ec][lane] = ebits[((size_t)b * CE + (ec << 6) + lane) * 16 + nc];
    __syncthreads();
    unsigned long long out = 0;
#pragma unroll
    for (int j = 0; j < 64; ++j)
        out |= ((w[ec][j] >> lane) & 1ull) << j;
    nbits[((size_t)b * CN + (nc << 6) + lane) * 8 + ec] = out;
}

// ---------- member lists: mem[gw][0..deg) = ascending node ids of edge gw ----------
__global__ void k_members(const unsigned long long* __restrict__ ebits,
                          unsigned short* __restrict__ mem, int* __restrict__ degs) {
    int gw = (blockIdx.x * blockDim.x + threadIdx.x) >> 6;
    int lane = threadIdx.x & 63;
    const unsigned long long* eb = ebits + (size_t)gw * 16;
    unsigned short* lst = mem + (size_t)gw * MCAP;
    int base = 0;
    unsigned long long lmask = (1ull << lane) - 1ull;
#pragma unroll
    for (int c = 0; c < 16; ++c) {
        unsigned long long w = eb[c];
        if ((w >> lane) & 1ull) {
            int off = base + (int)__popcll(w & lmask);
            if (off < MCAP) lst[off] = (unsigned short)((c << 6) + lane);
        }
        base += (int)__popcll(w);
    }
    if (lane == 0) degs[gw] = base;   // may exceed MCAP -> fallback path
}

// ---------- k_prep: vecs = 6 folded attention vectors ----------
__global__ void k_prep(const float* __restrict__ w2_1, const float* __restrict__ w3_1,
                       const float* __restrict__ a_1, const float* __restrict__ a2_1,
                       const float* __restrict__ w2_2, const float* __restrict__ w3_2,
                       const float* __restrict__ a_2, const float* __restrict__ a2_2,
                       float* __restrict__ vecs) {
    int which = blockIdx.x;
    int t = threadIdx.x;
    if (t >= CD) return;
    const float* W; const float* v;
    switch (which) {
        case 0:  W = w2_1; v = a_1 + CD;  break;
        case 1:  W = w2_1; v = a2_1;      break;
        case 2:  W = w3_1; v = a2_1 + CD; break;
        case 3:  W = w2_2; v = a_2 + CD;  break;
        case 4:  W = w2_2; v = a2_2;      break;
        default: W = w3_2; v = a2_2 + CD; break;
    }
    float s = 0.f;
    for (int j = 0; j < CD; ++j) s += W[(size_t)t * CD + j] * v[j];
    vecs[which * CD + t] = s;
}

// ---------- C[M,300] = A[M,300(lda)] @ W[300,300] ----------
__global__ __launch_bounds__(256) void k_gemm300(const float* __restrict__ A,
                                                 const float* __restrict__ W,
                                                 float* __restrict__ C, int M,
                                                 int lda, int ldc) {
    __shared__ float As[64][20];
    __shared__ float Ws[16][68];
    int tid = threadIdx.x;
    int n0 = blockIdx.x * 64, m0 = blockIdx.y * 64;
    int tx = tid & 15, ty = tid >> 4;
    int la_r = tid >> 2, la_c = (tid & 3) << 2;
    int lw_r = tid >> 4, lw_c = (tid & 15) << 2;
    float acc[4][4] = {};
    for (int k0 = 0; k0 < CD; k0 += 16) {
        {
            int kc = k0 + la_c;
            const float* Ap = A + (size_t)(m0 + la_r) * lda + kc;
            float4 av;
            if (kc + 3 < CD) av = *reinterpret_cast<const float4*>(Ap);
            else {
                av.x = kc     < CD ? Ap[0] : 0.f;
                av.y = kc + 1 < CD ? Ap[1] : 0.f;
                av.z = kc + 2 < CD ? Ap[2] : 0.f;
                av.w = 0.f;
            }
            *reinterpret_cast<float4*>(&As[la_r][la_c]) = av;
        }
        {
            int kr = k0 + lw_r;
            float4 wv = {0.f, 0.f, 0.f, 0.f};
            if (kr < CD) {
                const float* Wp = W + (size_t)kr * CD + n0 + lw_c;
                if (n0 + lw_c + 3 < CD) wv = *reinterpret_cast<const float4*>(Wp);
                else {
                    if (n0 + lw_c     < CD) wv.x = Wp[0];
                    if (n0 + lw_c + 1 < CD) wv.y = Wp[1];
                    if (n0 + lw_c + 2 < CD) wv.z = Wp[2];
                }
            }
            *reinterpret_cast<float4*>(&Ws[lw_r][lw_c]) = wv;
        }
        __syncthreads();
#pragma unroll
        for (int k = 0; k < 16; ++k) {
            float av[4];
#pragma unroll
            for (int i = 0; i < 4; ++i) av[i] = As[ty * 4 + i][k];
            float4 bv = *reinterpret_cast<const float4*>(&Ws[k][tx * 4]);
            float bb[4] = {bv.x, bv.y, bv.z, bv.w};
#pragma unroll
            for (int i = 0; i < 4; ++i)
#pragma unroll
                for (int j = 0; j < 4; ++j) acc[i][j] += av[i] * bb[j];
        }
        __syncthreads();
    }
    for (int i = 0; i < 4; ++i) {
        int m = m0 + ty * 4 + i;
        int n = n0 + tx * 4;
        float* Cp = C + (size_t)m * ldc + n;
        if (n + 3 < CD) {
            float4 v = {acc[i][0], acc[i][1], acc[i][2], acc[i][3]};
            *reinterpret_cast<float4*>(Cp) = v;
        } else {
            for (int j = 0; j < 4; ++j) if (n + j < CD) Cp[j] = acc[i][j];
        }
    }
}

// ---------- s1[r] = leaky(wc·a_top + X[r,:]·av), p[r] = X[r,:]·pv ----------
__global__ void k_score(const float* __restrict__ X, const float* __restrict__ av,
                        const float* __restrict__ pv, const float* __restrict__ wc,
                        const float* __restrict__ a_orig,
                        float alpha, float* __restrict__ s1, float* __restrict__ p, int M) {
    int gw = (blockIdx.x * blockDim.x + threadIdx.x) >> 6;
    int lane = threadIdx.x & 63;
    if (gw >= M) return;
    const float* row = X + (size_t)gw * CD;
    float d1 = 0.f, d2 = 0.f, dc = 0.f;
    for (int d = lane; d < CD; d += 64) {
        float x = row[d];
        d1 += x * av[d];
        d2 += x * pv[d];
        dc += wc[d] * a_orig[d];
    }
    for (int o = 32; o; o >>= 1) {
        d1 += __shfl_down(d1, o);
        d2 += __shfl_down(d2, o);
        dc += __shfl_down(dc, o);
    }
    if (lane == 0) {
        float v = dc + d1;
        s1[gw] = v > 0.f ? v : alpha * v;
        p[gw] = d2;
    }
}

// ---------- per-batch max over s1, e1 = exp(s1 - max) ----------
__global__ __launch_bounds__(1024) void k_bmax(const float* __restrict__ s1,
                                               float* __restrict__ e1) {
    __shared__ float red[16];
    int b = blockIdx.x, t = threadIdx.x;
    float v = s1[b * CN + t];
    float m = v;
    for (int o = 32; o; o >>= 1) m = fmaxf(m, __shfl_xor(m, o));
    if ((t & 63) == 0) red[t >> 6] = m;
    __syncthreads();
    if (t == 0) {
        float mm = red[0];
        for (int i = 1; i < 16; ++i) mm = fmaxf(mm, red[i]);
        red[0] = mm;
    }
    __syncthreads();
    e1[b * CN + t] = __expf(v - red[0]);
}

// ---------- sparse edge aggregation + fused q (CSR list, scalar slots, unroll-8) ----------
// R8-proven scalar-slot body (lane owns dims lane, lane+64, ..., lane+256), CSR
// counted loop; unroll widened 4->8 members for 2x outstanding loads (latency-bound
// gather). Per-dim member summation order identical to R8 -> edge values unchanged.
__global__ __launch_bounds__(256) void k_edge_agg(const unsigned short* __restrict__ mem,
        const int* __restrict__ degs, const unsigned long long* __restrict__ ebits,
        const float* __restrict__ e1, const float* __restrict__ Xs,
        const float* __restrict__ qvec, float* __restrict__ edge, float* __restrict__ q) {
    int gw = (blockIdx.x * blockDim.x + threadIdx.x) >> 6;   // b*CE + e
    int lane = threadIdx.x & 63;
    int b = gw >> 9;
    const float* e1b = e1 + b * CN;
    const float* Xb = Xs + (size_t)b * CN * CD;
    int deg = degs[gw];
    float a0 = 0.f, a1 = 0.f, a2 = 0.f, a3 = 0.f, a4 = 0.f;
    float den = 0.f;
    bool tail = lane < (CD - 256);
    if (deg <= MCAP) {
        const unsigned short* lst = mem + (size_t)gw * MCAP;
        int i = 0;
        for (; i + 8 <= deg; i += 8) {
            ushort4 na = *reinterpret_cast<const ushort4*>(lst + i);
            ushort4 nb = *reinterpret_cast<const ushort4*>(lst + i + 4);
            float w0 = e1b[na.x], w1 = e1b[na.y], w2 = e1b[na.z], w3 = e1b[na.w];
            float w4 = e1b[nb.x], w5 = e1b[nb.y], w6 = e1b[nb.z], w7 = e1b[nb.w];
            const float* r0 = Xb + (size_t)na.x * CD;
            const float* r1 = Xb + (size_t)na.y * CD;
            const float* r2 = Xb + (size_t)na.z * CD;
            const float* r3 = Xb + (size_t)na.w * CD;
            const float* r4 = Xb + (size_t)nb.x * CD;
            const float* r5 = Xb + (size_t)nb.y * CD;
            const float* r6 = Xb + (size_t)nb.z * CD;
            const float* r7 = Xb + (size_t)nb.w * CD;
            float v00 = r0[lane], v01 = r0[lane + 64], v02 = r0[lane + 128], v03 = r0[lane + 192];
            float v10 = r1[lane], v11 = r1[lane + 64], v12 = r1[lane + 128], v13 = r1[lane + 192];
            float v20 = r2[lane], v21 = r2[lane + 64], v22 = r2[lane + 128], v23 = r2[lane + 192];
            float v30 = r3[lane], v31 = r3[lane + 64], v32 = r3[lane + 128], v33 = r3[lane + 192];
            float v40 = r4[lane], v41 = r4[lane + 64], v42 = r4[lane + 128], v43 = r4[lane + 192];
            float v50 = r5[lane], v51 = r5[lane + 64], v52 = r5[lane + 128], v53 = r5[lane + 192];
            float v60 = r6[lane], v61 = r6[lane + 64], v62 = r6[lane + 128], v63 = r6[lane + 192];
            float v70 = r7[lane], v71 = r7[lane + 64], v72 = r7[lane + 128], v73 = r7[lane + 192];
            float v04 = 0.f, v14 = 0.f, v24 = 0.f, v34 = 0.f;
            float v44 = 0.f, v54 = 0.f, v64 = 0.f, v74 = 0.f;
            if (tail) {
                v04 = r0[lane + 256]; v14 = r1[lane + 256]; v24 = r2[lane + 256]; v34 = r3[lane + 256];
                v44 = r4[lane + 256]; v54 = r5[lane + 256]; v64 = r6[lane + 256]; v74 = r7[lane + 256];
            }
            den += w0; den += w1; den += w2; den += w3;
            den += w4; den += w5; den += w6; den += w7;
            a0 += w0 * v00; a0 += w1 * v10; a0 += w2 * v20; a0 += w3 * v30;
            a0 += w4 * v40; a0 += w5 * v50; a0 += w6 * v60; a0 += w7 * v70;
            a1 += w0 * v01; a1 += w1 * v11; a1 += w2 * v21; a1 += w3 * v31;
            a1 += w4 * v41; a1 += w5 * v51; a1 += w6 * v61; a1 += w7 * v71;
            a2 += w0 * v02; a2 += w1 * v12; a2 += w2 * v22; a2 += w3 * v32;
            a2 += w4 * v42; a2 += w5 * v52; a2 += w6 * v62; a2 += w7 * v72;
            a3 += w0 * v03; a3 += w1 * v13; a3 += w2 * v23; a3 += w3 * v33;
            a3 += w4 * v43; a3 += w5 * v53; a3 += w6 * v63; a3 += w7 * v73;
            a4 += w0 * v04; a4 += w1 * v14; a4 += w2 * v24; a4 += w3 * v34;
            a4 += w4 * v44; a4 += w5 * v54; a4 += w6 * v64; a4 += w7 * v74;
        }
        for (; i + 4 <= deg; i += 4) {
            ushort4 nn = *reinterpret_cast<const ushort4*>(lst + i);
            float w0 = e1b[nn.x], w1 = e1b[nn.y], w2 = e1b[nn.z], w3 = e1b[nn.w];
            const float* r0 = Xb + (size_t)nn.x * CD;
            const float* r1 = Xb + (size_t)nn.y * CD;
            const float* r2 = Xb + (size_t)nn.z * CD;
            const float* r3 = Xb + (size_t)nn.w * CD;
            float v00 = r0[lane], v01 = r0[lane + 64], v02 = r0[lane + 128], v03 = r0[lane + 192];
            float v10 = r1[lane], v11 = r1[lane + 64], v12 = r1[lane + 128], v13 = r1[lane + 192];
            float v20 = r2[lane], v21 = r2[lane + 64], v22 = r2[lane + 128], v23 = r2[lane + 192];
            float v30 = r3[lane], v31 = r3[lane + 64], v32 = r3[lane + 128], v33 = r3[lane + 192];
            float v04 = 0.f, v14 = 0.f, v24 = 0.f, v34 = 0.f;
            if (tail) { v04 = r0[lane + 256]; v14 = r1[lane + 256]; v24 = r2[lane + 256]; v34 = r3[lane + 256]; }
            den += w0; den += w1; den += w2; den += w3;
            a0 += w0 * v00; a0 += w1 * v10; a0 += w2 * v20; a0 += w3 * v30;
            a1 += w0 * v01; a1 += w1 * v11; a1 += w2 * v21; a1 += w3 * v31;
            a2 += w0 * v02; a2 += w1 * v12; a2 += w2 * v22; a2 += w3 * v32;
            a3 += w0 * v03; a3 += w1 * v13; a3 += w2 * v23; a3 += w3 * v33;
            a4 += w0 * v04; a4 += w1 * v14; a4 += w2 * v24; a4 += w3 * v34;
        }
        for (; i < deg; ++i) {
            int n = lst[i];
            float w = e1b[n];
            const float* r = Xb + (size_t)n * CD;
            den += w;
            a0 += w * r[lane];
            a1 += w * r[lane + 64];
            a2 += w * r[lane + 128];
            a3 += w * r[lane + 192];
            if (tail) a4 += w * r[lane + 256];
        }
    } else {   // overflow fallback (P~1e-20): ebits/ballot path
        const unsigned long long* eb = ebits + (size_t)gw * 16;
#pragma unroll
        for (int c = 0; c < 16; ++c) {
            int n0 = c << 6;
            float wv = e1b[n0 + lane];
            unsigned long long bal = eb[c];
            while (bal) {
                int jj = (int)__ffsll(bal) - 1;
                bal &= bal - 1ull;
                float w = __shfl(wv, jj);
                const float* row = Xb + (size_t)(n0 + jj) * CD;
                den += w;
                a0 += w * row[lane];
                a1 += w * row[lane + 64];
                a2 += w * row[lane + 128];
                a3 += w * row[lane + 192];
                if (tail) a4 += w * row[lane + 256];
            }
        }
    }
    float inv = deg > 0 ? 1.f / den : 0.f;
    float o0 = a0 * inv, o1 = a1 * inv, o2 = a2 * inv, o3 = a3 * inv;
    float o4 = tail ? a4 * inv : 0.f;
    float* erow = edge + (size_t)gw * EP;
    erow[lane]       = o0;
    erow[lane + 64]  = o1;
    erow[lane + 128] = o2;
    erow[lane + 192] = o3;
    erow[lane + 256] = o4;
    float d2 = o0 * qvec[lane];
    d2 += o1 * qvec[lane + 64];
    d2 += o2 * qvec[lane + 128];
    d2 += o3 * qvec[lane + 192];
    if (tail) d2 += o4 * qvec[lane + 256];
    for (int o = 32; o; o >>= 1) d2 += __shfl_down(d2, o);
    if (lane == 0) q[gw] = d2;
}

// ---------- fused node attention (R8-proven): nbits masks + compacted weights ----------
#define ACC16(vv, ww) do { \
    acc[0][0] += (ww).x * (vv).x; acc[0][1] += (ww).x * (vv).y; \
    acc[0][2] += (ww).x * (vv).z; acc[0][3] += (ww).x * (vv).w; \
    acc[1][0] += (ww).y * (vv).x; acc[1][1] += (ww).y * (vv).y; \
    acc[1][2] += (ww).y * (vv).z; acc[1][3] += (ww).y * (vv).w; \
    acc[2][0] += (ww).z * (vv).x; acc[2][1] += (ww).z * (vv).y; \
    acc[2][2] += (ww).z * (vv).z; acc[2][3] += (ww).z * (vv).w; \
    acc[3][0] += (ww).w * (vv).x; acc[3][1] += (ww).w * (vv).y; \
    acc[3][2] += (ww).w * (vv).z; acc[3][3] += (ww).w * (vv).w; \
} while (0)

__global__ __launch_bounds__(320) void k_node_attn(const unsigned long long* __restrict__ nbits,
        const float* __restrict__ p, const float* __restrict__ q,
        const float* __restrict__ edge, float alpha, int do_elu, float* __restrict__ out) {
    __shared__ float4 wsc[4][UCAP];
    __shared__ __align__(8) unsigned short ul[4][UCAP];
    __shared__ int ucnt_s[4], flag_s[4];
    __shared__ float gpn[16], gmx[16], gsc[16];
    __shared__ int gct[16];
    int blk = blockIdx.x;
    int b = blk >> 6, n0 = (blk & 63) << 4;
    int tid = threadIdx.x, wv = tid >> 6, lane = tid & 63;
    const float* qb = q + b * CE;

    if (wv < 4) {
        float pn[4]; const unsigned long long* nb[4];
#pragma unroll
        for (int k = 0; k < 4; ++k) {
            int n = n0 + 4 * wv + k;
            pn[k] = p[b * CN + n];
            nb[k] = nbits + ((size_t)b * CN + n) * 8;
        }
        float sc[4][8];
        int cnt[4] = {0, 0, 0, 0};
        float mx[4] = {-3.4e38f, -3.4e38f, -3.4e38f, -3.4e38f};
        int ubits = 0;
#pragma unroll
        for (int j = 0; j < 8; ++j) {
            int e = lane + (j << 6);
            float qe = qb[e];
            int many = 0;
#pragma unroll
            for (int k = 0; k < 4; ++k) {
                int m = (int)((nb[k][j] >> lane) & 1ull);
                float v = pn[k] + qe;
                v = v > 0.f ? v : alpha * v;
                v = m ? v : -3.0e38f;
                cnt[k] += m; many |= m;
                mx[k] = fmaxf(mx[k], v);
                sc[k][j] = v;
            }
            ubits |= (many ? 1 : 0) << j;
        }
#pragma unroll
        for (int k = 0; k < 4; ++k) {
            for (int o = 32; o; o >>= 1) {
                mx[k] = fmaxf(mx[k], __shfl_xor(mx[k], o));
                cnt[k] += __shfl_xor(cnt[k], o);
            }
        }
        float scale[4];
#pragma unroll
        for (int k = 0; k < 4; ++k) {
            float s = 0.f;
#pragma unroll
            for (int j = 0; j < 8; ++j) { float w8 = __expf(sc[k][j] - mx[k]); sc[k][j] = w8; s += w8; }
            for (int o = 32; o; o >>= 1) s += __shfl_xor(s, o);
            scale[k] = cnt[k] > 0 ? 1.f / s : 1.f;
        }
        int base = 0;
        unsigned long long lmask = (1ull << lane) - 1ull;
#pragma unroll
        for (int j = 0; j < 8; ++j) {
            unsigned long long bal = __ballot((ubits >> j) & 1);
            if ((ubits >> j) & 1) {
                int off = base + (int)__popcll(bal & lmask);
                if (off < UCAP) {
                    ul[wv][off] = (unsigned short)(lane + (j << 6));
                    wsc[wv][off] = make_float4(sc[0][j] * scale[0], sc[1][j] * scale[1],
                                               sc[2][j] * scale[2], sc[3][j] * scale[3]);
                }
            }
            base += (int)__popcll(bal);
        }
        if (lane == 0) {
            ucnt_s[wv] = base < UCAP ? base : UCAP;
            flag_s[wv] = (cnt[0] == 0) | (cnt[1] == 0) | (cnt[2] == 0) | (cnt[3] == 0) |
                         (base > UCAP);
            gpn[wv*4+0]=pn[0]; gmx[wv*4+0]=mx[0]; gsc[wv*4+0]=scale[0]; gct[wv*4+0]=cnt[0];
            gpn[wv*4+1]=pn[1]; gmx[wv*4+1]=mx[1]; gsc[wv*4+1]=scale[1]; gct[wv*4+1]=cnt[1];
            gpn[wv*4+2]=pn[2]; gmx[wv*4+2]=mx[2]; gsc[wv*4+2]=scale[2]; gct[wv*4+2]=cnt[2];
            gpn[wv*4+3]=pn[3]; gmx[wv*4+3]=mx[3]; gsc[wv*4+3]=scale[3]; gct[wv*4+3]=cnt[3];
        }
    }
    __syncthreads();

    int grp = tid / 80;
    int j4 = tid - grp * 80;
    const float4* eb4 = reinterpret_cast<const float4*>(edge + (size_t)b * CE * EP) + j4;
    int cnt = ucnt_s[grp], bad = flag_s[grp];
    float acc[4][4] = {};
    if (!bad) {
        int i = 0;
        for (; i + 8 <= cnt; i += 8) {
            ushort4 ua = *reinterpret_cast<const ushort4*>(&ul[grp][i]);
            ushort4 ub = *reinterpret_cast<const ushort4*>(&ul[grp][i + 4]);
            float4 v0 = eb4[(size_t)ua.x * 80], v1 = eb4[(size_t)ua.y * 80];
            float4 v2 = eb4[(size_t)ua.z * 80], v3 = eb4[(size_t)ua.w * 80];
            float4 v4 = eb4[(size_t)ub.x * 80], v5 = eb4[(size_t)ub.y * 80];
            float4 v6 = eb4[(size_t)ub.z * 80], v7 = eb4[(size_t)ub.w * 80];
            { float4 w = wsc[grp][i];     ACC16(v0, w); }
            { float4 w = wsc[grp][i + 1]; ACC16(v1, w); }
            { float4 w = wsc[grp][i + 2]; ACC16(v2, w); }
            { float4 w = wsc[grp][i + 3]; ACC16(v3, w); }
            { float4 w = wsc[grp][i + 4]; ACC16(v4, w); }
            { float4 w = wsc[grp][i + 5]; ACC16(v5, w); }
            { float4 w = wsc[grp][i + 6]; ACC16(v6, w); }
            { float4 w = wsc[grp][i + 7]; ACC16(v7, w); }
        }
        for (; i < cnt; ++i) {
            int e = ul[grp][i];
            float4 v = eb4[(size_t)e * 80];
            float4 w = wsc[grp][i];
            ACC16(v, w);
        }
    } else {
        float pnk[4], mxk[4], sck[4]; int ctk[4];
        const unsigned long long* nbr[4];
#pragma unroll
        for (int k = 0; k < 4; ++k) {
            pnk[k] = gpn[grp*4+k]; mxk[k] = gmx[grp*4+k]; sck[k] = gsc[grp*4+k]; ctk[k] = gct[grp*4+k];
            nbr[k] = nbits + ((size_t)b * CN + n0 + grp * 4 + k) * 8;
        }
        for (int e = 0; e < CE; ++e) {
            float4 v = eb4[(size_t)e * 80];
            float qe = qb[e];
#pragma unroll
            for (int k = 0; k < 4; ++k) {
                int m = (int)((nbr[k][e >> 6] >> (e & 63)) & 1ull);
                float vv = pnk[k] + qe; vv = vv > 0.f ? vv : alpha * vv;
                float w = ctk[k] == 0 ? (1.f / CE) : (m ? __expf(vv - mxk[k]) * sck[k] : 0.f);
                acc[k][0] += w * v.x; acc[k][1] += w * v.y; acc[k][2] += w * v.z; acc[k][3] += w * v.w;
            }
        }
    }
    if (j4 < 75) {
#pragma unroll
        for (int ni = 0; ni < 4; ++ni) {
            float4 o = {acc[ni][0], acc[ni][1], acc[ni][2], acc[ni][3]};
            if (do_elu) {
                o.x = o.x > 0.f ? o.x : expm1f(o.x);
                o.y = o.y > 0.f ? o.y : expm1f(o.y);
                o.z = o.z > 0.f ? o.z : expm1f(o.z);
                o.w = o.w > 0.f ? o.w : expm1f(o.w);
            }
            *reinterpret_cast<float4*>(out + ((size_t)b * CN + n0 + grp * 4 + ni) * CD + j4 * 4) = o;
        }
    }
}

extern "C" void kernel_launch(void* const* d_in, const int* in_sizes, int n_in,
                              void* d_out, int out_size, void* d_ws, size_t ws_size,
                              hipStream_t stream) {
    const int*   inputs = (const int*)d_in[0];
    const int*   HT     = (const int*)d_in[1];
    const float* emb    = (const float*)d_in[2];
    const float* w2_1   = (const float*)d_in[3];
    const float* w3_1   = (const float*)d_in[4];
    const float* a_1    = (const float*)d_in[5];
    const float* a2_1   = (const float*)d_in[6];
    const float* wc_1   = (const float*)d_in[7];
    const float* w_2    = (const float*)d_in[8];
    const float* w2_2   = (const float*)d_in[9];
    const float* w3_2   = (const float*)d_in[10];
    const float* a_2    = (const float*)d_in[11];
    const float* a2_2   = (const float*)d_in[12];
    const float* wc_2   = (const float*)d_in[13];

    char* ws = (char*)d_ws;
    float* big0               = (float*)(ws);                          // 39,321,600 B: X0 -> X1
    float* big1               = (float*)(ws + 39321600);               // 39,321,600 B: XW
    float* edge               = (float*)(ws + 78643200);               // 20,971,520 B (EP=320)
    unsigned long long* ebits = (unsigned long long*)(ws + 99614720);  //  2,097,152 B
    unsigned long long* nbits = (unsigned long long*)(ws + 101711872); //  2,097,152 B
    unsigned short* mem       = (unsigned short*)(ws + 103809024);     //  6,291,456 B
    int* degs                 = (int*)(ws + 110100480);                //     65,536 B
    float* s1                 = (float*)(ws + 110166016);              //    131,072 B
    float* p                  = (float*)(ws + 110297088);              //    131,072 B
    float* e1                 = (float*)(ws + 110428160);              //    131,072 B
    float* qv                 = (float*)(ws + 110559232);              //     65,536 B
    float* vecs               = (float*)(ws + 110624768);              //      7,200 B
    // total: 110,631,968 B

    k_embed<<<9600, 256, 0, stream>>>(inputs, emb, big0);
    k_ebits<<<4096, 256, 0, stream>>>(HT, ebits);
    k_bitT<<<512, 512, 0, stream>>>(ebits, nbits);
    k_members<<<4096, 256, 0, stream>>>(ebits, mem, degs);
    k_prep<<<6, 320, 0, stream>>>(w2_1, w3_1, a_1, a2_1, w2_2, w3_2, a_2, a2_2, vecs);

    // ---- layer 1: transfer=False, concat=True (ELU), alpha=0.1 ----
    k_score<<<CB * CN / 4, 256, 0, stream>>>(big0, vecs, vecs + CD, wc_1, a_1, 0.1f, s1, p, CB * CN);
    k_bmax<<<CB, 1024, 0, stream>>>(s1, e1);
    k_edge_agg<<<4096, 256, 0, stream>>>(mem, degs, ebits, e1, big0, vecs + 2 * CD, edge, qv);
    k_node_attn<<<2048, 320, 0, stream>>>(nbits, p, qv, edge, 0.1f, 1, big0);   // X1 -> big0

    // ---- layer 2: transfer=True, concat=False, alpha=0.2 ----
    k_score<<<CB * CN / 4, 256, 0, stream>>>(big0, vecs + 3 * CD, vecs + 4 * CD, wc_2, a_2, 0.2f, s1, p, CB * CN);
    k_gemm300<<<dim3(5, 512), 256, 0, stream>>>(big0, w_2, big1, CB * CN, CD, CD);   // XW = X1 @ w_2
    k_bmax<<<CB, 1024, 0, stream>>>(s1, e1);
    k_edge_agg<<<4096, 256, 0, stream>>>(mem, degs, ebits, e1, big1, vecs + 5 * CD, edge, qv);
    k_node_attn<<<2048, 320, 0, stream>>>(nbits, p, qv, edge, 0.2f, 0, (float*)d_out);
}

// Round 13
// 601.135 us; speedup vs baseline: 1.1719x; 1.0662x over previous
//
#include <hip/hip_runtime.h>
#include <hip/hip_bf16.h>

#define CB 32
#define CN 1024
#define CE 512
#define CD 300
#define EP 320    // padded edge-row stride (floats); pad cols [300,320) are written 0
#define UCAP 320  // union-list capacity per 4-node group (mean 176, sd ~11)
#define MCAP 192  // member-list capacity per edge (deg ~ B(1024,.1): mean 102, sd 9.6)

// ---------- embedding gather: X[r,:] = emb[idx[r],:] ----------
__global__ void k_embed(const int* __restrict__ idx, const float* __restrict__ emb,
                        float* __restrict__ X) {
    int gid = blockIdx.x * blockDim.x + threadIdx.x;
    const int total = CB * CN * 75;
    if (gid >= total) return;
    int r = gid / 75, c = gid % 75;
    int e = idx[r];
    reinterpret_cast<float4*>(X)[(size_t)r * 75 + c] =
        reinterpret_cast<const float4*>(emb)[(size_t)e * 75 + c];
}

// ---------- fused: ebits words + CSR member list per edge (one wave per edge) ----------
__global__ void k_ebits_mem(const int* __restrict__ HT, unsigned long long* __restrict__ ebits,
                            unsigned short* __restrict__ mem, int* __restrict__ degs) {
    int gw = (blockIdx.x * blockDim.x + threadIdx.x) >> 6;   // b*CE+e
    int lane = threadIdx.x & 63;
    const int* hrow = HT + (size_t)gw * CN;
    unsigned short* lst = mem + (size_t)gw * MCAP;
    int base = 0;
    unsigned long long lmask = (1ull << lane) - 1ull;
#pragma unroll
    for (int c = 0; c < 16; ++c) {
        unsigned long long bal = __ballot(hrow[(c << 6) + lane] != 0);
        if (lane == 0) ebits[(size_t)gw * 16 + c] = bal;
        if ((bal >> lane) & 1ull) {
            int off = base + (int)__popcll(bal & lmask);
            if (off < MCAP) lst[off] = (unsigned short)((c << 6) + lane);
        }
        base += (int)__popcll(bal);
    }
    if (lane == 0) degs[gw] = base;   // may exceed MCAP -> fallback path
}

// ---------- nbits = bit-transpose of ebits ----------
__global__ __launch_bounds__(512) void k_bitT(const unsigned long long* __restrict__ ebits,
        unsigned long long* __restrict__ nbits) {
    __shared__ unsigned long long w[8][64];
    int b = blockIdx.x >> 4, nc = blockIdx.x & 15;
    int tid = threadIdx.x, ec = tid >> 6, lane = tid & 63;
    w[ec][lane] = ebits[((size_t)b * CE + (ec << 6) + lane) * 16 + nc];
    __syncthreads();
    unsigned long long out = 0;
#pragma unroll
    for (int j = 0; j < 64; ++j)
        out |= ((w[ec][j] >> lane) & 1ull) << j;
    nbits[((size_t)b * CN + (nc << 6) + lane) * 8 + ec] = out;
}

// ---------- k_prep: vecs = 6 folded attention vectors ----------
__global__ void k_prep(const float* __restrict__ w2_1, const float* __restrict__ w3_1,
                       const float* __restrict__ a_1, const float* __restrict__ a2_1,
                       const float* __restrict__ w2_2, const float* __restrict__ w3_2,
                       const float* __restrict__ a_2, const float* __restrict__ a2_2,
                       float* __restrict__ vecs) {
    int which = blockIdx.x;
    int t = threadIdx.x;
    if (t >= CD) return;
    const float* W; const float* v;
    switch (which) {
        case 0:  W = w2_1; v = a_1 + CD;  break;
        case 1:  W = w2_1; v = a2_1;      break;
        case 2:  W = w3_1; v = a2_1 + CD; break;
        case 3:  W = w2_2; v = a_2 + CD;  break;
        case 4:  W = w2_2; v = a2_2;      break;
        default: W = w3_2; v = a2_2 + CD; break;
    }
    float s = 0.f;
    for (int j = 0; j < CD; ++j) s += W[(size_t)t * CD + j] * v[j];
    vecs[which * CD + t] = s;
}

// ---------- C[M,300] = A[M,300(lda)] @ W[300,300] ----------
__global__ __launch_bounds__(256) void k_gemm300(const float* __restrict__ A,
                                                 const float* __restrict__ W,
                                                 float* __restrict__ C, int M,
                                                 int lda, int ldc) {
    __shared__ float As[64][20];
    __shared__ float Ws[16][68];
    int tid = threadIdx.x;
    int n0 = blockIdx.x * 64, m0 = blockIdx.y * 64;
    int tx = tid & 15, ty = tid >> 4;
    int la_r = tid >> 2, la_c = (tid & 3) << 2;
    int lw_r = tid >> 4, lw_c = (tid & 15) << 2;
    float acc[4][4] = {};
    for (int k0 = 0; k0 < CD; k0 += 16) {
        {
            int kc = k0 + la_c;
            const float* Ap = A + (size_t)(m0 + la_r) * lda + kc;
            float4 av;
            if (kc + 3 < CD) av = *reinterpret_cast<const float4*>(Ap);
            else {
                av.x = kc     < CD ? Ap[0] : 0.f;
                av.y = kc + 1 < CD ? Ap[1] : 0.f;
                av.z = kc + 2 < CD ? Ap[2] : 0.f;
                av.w = 0.f;
            }
            *reinterpret_cast<float4*>(&As[la_r][la_c]) = av;
        }
        {
            int kr = k0 + lw_r;
            float4 wv = {0.f, 0.f, 0.f, 0.f};
            if (kr < CD) {
                const float* Wp = W + (size_t)kr * CD + n0 + lw_c;
                if (n0 + lw_c + 3 < CD) wv = *reinterpret_cast<const float4*>(Wp);
                else {
                    if (n0 + lw_c     < CD) wv.x = Wp[0];
                    if (n0 + lw_c + 1 < CD) wv.y = Wp[1];
                    if (n0 + lw_c + 2 < CD) wv.z = Wp[2];
                }
            }
            *reinterpret_cast<float4*>(&Ws[lw_r][lw_c]) = wv;
        }
        __syncthreads();
#pragma unroll
        for (int k = 0; k < 16; ++k) {
            float av[4];
#pragma unroll
            for (int i = 0; i < 4; ++i) av[i] = As[ty * 4 + i][k];
            float4 bv = *reinterpret_cast<const float4*>(&Ws[k][tx * 4]);
            float bb[4] = {bv.x, bv.y, bv.z, bv.w};
#pragma unroll
            for (int i = 0; i < 4; ++i)
#pragma unroll
                for (int j = 0; j < 4; ++j) acc[i][j] += av[i] * bb[j];
        }
        __syncthreads();
    }
    for (int i = 0; i < 4; ++i) {
        int m = m0 + ty * 4 + i;
        int n = n0 + tx * 4;
        float* Cp = C + (size_t)m * ldc + n;
        if (n + 3 < CD) {
            float4 v = {acc[i][0], acc[i][1], acc[i][2], acc[i][3]};
            *reinterpret_cast<float4*>(Cp) = v;
        } else {
            for (int j = 0; j < 4; ++j) if (n + j < CD) Cp[j] = acc[i][j];
        }
    }
}

// ---------- s1[r] = leaky(wc·a_top + X[r,:]·av), p[r] = X[r,:]·pv ----------
__global__ void k_score(const float* __restrict__ X, const float* __restrict__ av,
                        const float* __restrict__ pv, const float* __restrict__ wc,
                        const float* __restrict__ a_orig,
                        float alpha, float* __restrict__ s1, float* __restrict__ p, int M) {
    int gw = (blockIdx.x * blockDim.x + threadIdx.x) >> 6;
    int lane = threadIdx.x & 63;
    if (gw >= M) return;
    const float* row = X + (size_t)gw * CD;
    float d1 = 0.f, d2 = 0.f, dc = 0.f;
    for (int d = lane; d < CD; d += 64) {
        float x = row[d];
        d1 += x * av[d];
        d2 += x * pv[d];
        dc += wc[d] * a_orig[d];
    }
    for (int o = 32; o; o >>= 1) {
        d1 += __shfl_down(d1, o);
        d2 += __shfl_down(d2, o);
        dc += __shfl_down(dc, o);
    }
    if (lane == 0) {
        float v = dc + d1;
        s1[gw] = v > 0.f ? v : alpha * v;
        p[gw] = d2;
    }
}

// ---------- per-batch max over s1, e1 = exp(s1 - max) ----------
__global__ __launch_bounds__(1024) void k_bmax(const float* __restrict__ s1,
                                               float* __restrict__ e1) {
    __shared__ float red[16];
    int b = blockIdx.x, t = threadIdx.x;
    float v = s1[b * CN + t];
    float m = v;
    for (int o = 32; o; o >>= 1) m = fmaxf(m, __shfl_xor(m, o));
    if ((t & 63) == 0) red[t >> 6] = m;
    __syncthreads();
    if (t == 0) {
        float mm = red[0];
        for (int i = 1; i < 16; ++i) mm = fmaxf(mm, red[i]);
        red[0] = mm;
    }
    __syncthreads();
    e1[b * CN + t] = __expf(v - red[0]);
}

// ---------- sparse edge aggregation + fused q (CSR, unroll-8, XCD-pinned batches) ----------
// Block i -> batch b with b%8 == i%8 (bijective, 4096%8==0): each XCD's L2 keeps
// its 4 batches' X rows (~4.8 MB) resident across the ~51x per-row reuse, instead
// of all XCDs thrashing the full 39 MB X. Body identical to R12 (bitwise-same).
__global__ __launch_bounds__(256) void k_edge_agg(const unsigned short* __restrict__ mem,
        const int* __restrict__ degs, const unsigned long long* __restrict__ ebits,
        const float* __restrict__ e1, const float* __restrict__ Xs,
        const float* __restrict__ qvec, float* __restrict__ edge, float* __restrict__ q) {
    int i0 = blockIdx.x;
    int r = i0 & 7, t = i0 >> 3;        // t in 0..511
    int b = (t >> 7) * 8 + r;           // 4 batches per XCD slot
    int j = t & 127;                    // edge-quad within batch
    int gw = b * CE + (j << 2) + (threadIdx.x >> 6);
    int lane = threadIdx.x & 63;
    const float* e1b = e1 + b * CN;
    const float* Xb = Xs + (size_t)b * CN * CD;
    int deg = degs[gw];
    float a0 = 0.f, a1 = 0.f, a2 = 0.f, a3 = 0.f, a4 = 0.f;
    float den = 0.f;
    bool tail = lane < (CD - 256);
    if (deg <= MCAP) {
        const unsigned short* lst = mem + (size_t)gw * MCAP;
        int i = 0;
        for (; i + 8 <= deg; i += 8) {
            ushort4 na = *reinterpret_cast<const ushort4*>(lst + i);
            ushort4 nb = *reinterpret_cast<const ushort4*>(lst + i + 4);
            float w0 = e1b[na.x], w1 = e1b[na.y], w2 = e1b[na.z], w3 = e1b[na.w];
            float w4 = e1b[nb.x], w5 = e1b[nb.y], w6 = e1b[nb.z], w7 = e1b[nb.w];
            const float* r0 = Xb + (size_t)na.x * CD;
            const float* r1 = Xb + (size_t)na.y * CD;
            const float* r2 = Xb + (size_t)na.z * CD;
            const float* r3 = Xb + (size_t)na.w * CD;
            const float* r4 = Xb + (size_t)nb.x * CD;
            const float* r5 = Xb + (size_t)nb.y * CD;
            const float* r6 = Xb + (size_t)nb.z * CD;
            const float* r7 = Xb + (size_t)nb.w * CD;
            float v00 = r0[lane], v01 = r0[lane + 64], v02 = r0[lane + 128], v03 = r0[lane + 192];
            float v10 = r1[lane], v11 = r1[lane + 64], v12 = r1[lane + 128], v13 = r1[lane + 192];
            float v20 = r2[lane], v21 = r2[lane + 64], v22 = r2[lane + 128], v23 = r2[lane + 192];
            float v30 = r3[lane], v31 = r3[lane + 64], v32 = r3[lane + 128], v33 = r3[lane + 192];
            float v40 = r4[lane], v41 = r4[lane + 64], v42 = r4[lane + 128], v43 = r4[lane + 192];
            float v50 = r5[lane], v51 = r5[lane + 64], v52 = r5[lane + 128], v53 = r5[lane + 192];
            float v60 = r6[lane], v61 = r6[lane + 64], v62 = r6[lane + 128], v63 = r6[lane + 192];
            float v70 = r7[lane], v71 = r7[lane + 64], v72 = r7[lane + 128], v73 = r7[lane + 192];
            float v04 = 0.f, v14 = 0.f, v24 = 0.f, v34 = 0.f;
            float v44 = 0.f, v54 = 0.f, v64 = 0.f, v74 = 0.f;
            if (tail) {
                v04 = r0[lane + 256]; v14 = r1[lane + 256]; v24 = r2[lane + 256]; v34 = r3[lane + 256];
                v44 = r4[lane + 256]; v54 = r5[lane + 256]; v64 = r6[lane + 256]; v74 = r7[lane + 256];
            }
            den += w0; den += w1; den += w2; den += w3;
            den += w4; den += w5; den += w6; den += w7;
            a0 += w0 * v00; a0 += w1 * v10; a0 += w2 * v20; a0 += w3 * v30;
            a0 += w4 * v40; a0 += w5 * v50; a0 += w6 * v60; a0 += w7 * v70;
            a1 += w0 * v01; a1 += w1 * v11; a1 += w2 * v21; a1 += w3 * v31;
            a1 += w4 * v41; a1 += w5 * v51; a1 += w6 * v61; a1 += w7 * v71;
            a2 += w0 * v02; a2 += w1 * v12; a2 += w2 * v22; a2 += w3 * v32;
            a2 += w4 * v42; a2 += w5 * v52; a2 += w6 * v62; a2 += w7 * v72;
            a3 += w0 * v03; a3 += w1 * v13; a3 += w2 * v23; a3 += w3 * v33;
            a3 += w4 * v43; a3 += w5 * v53; a3 += w6 * v63; a3 += w7 * v73;
            a4 += w0 * v04; a4 += w1 * v14; a4 += w2 * v24; a4 += w3 * v34;
            a4 += w4 * v44; a4 += w5 * v54; a4 += w6 * v64; a4 += w7 * v74;
        }
        for (; i + 4 <= deg; i += 4) {
            ushort4 nn = *reinterpret_cast<const ushort4*>(lst + i);
            float w0 = e1b[nn.x], w1 = e1b[nn.y], w2 = e1b[nn.z], w3 = e1b[nn.w];
            const float* r0 = Xb + (size_t)nn.x * CD;
            const float* r1 = Xb + (size_t)nn.y * CD;
            const float* r2 = Xb + (size_t)nn.z * CD;
            const float* r3 = Xb + (size_t)nn.w * CD;
            float v00 = r0[lane], v01 = r0[lane + 64], v02 = r0[lane + 128], v03 = r0[lane + 192];
            float v10 = r1[lane], v11 = r1[lane + 64], v12 = r1[lane + 128], v13 = r1[lane + 192];
            float v20 = r2[lane], v21 = r2[lane + 64], v22 = r2[lane + 128], v23 = r2[lane + 192];
            float v30 = r3[lane], v31 = r3[lane + 64], v32 = r3[lane + 128], v33 = r3[lane + 192];
            float v04 = 0.f, v14 = 0.f, v24 = 0.f, v34 = 0.f;
            if (tail) { v04 = r0[lane + 256]; v14 = r1[lane + 256]; v24 = r2[lane + 256]; v34 = r3[lane + 256]; }
            den += w0; den += w1; den += w2; den += w3;
            a0 += w0 * v00; a0 += w1 * v10; a0 += w2 * v20; a0 += w3 * v30;
            a1 += w0 * v01; a1 += w1 * v11; a1 += w2 * v21; a1 += w3 * v31;
            a2 += w0 * v02; a2 += w1 * v12; a2 += w2 * v22; a2 += w3 * v32;
            a3 += w0 * v03; a3 += w1 * v13; a3 += w2 * v23; a3 += w3 * v33;
            a4 += w0 * v04; a4 += w1 * v14; a4 += w2 * v24; a4 += w3 * v34;
        }
        for (; i < deg; ++i) {
            int n = lst[i];
            float w = e1b[n];
            const float* r = Xb + (size_t)n * CD;
            den += w;
            a0 += w * r[lane];
            a1 += w * r[lane + 64];
            a2 += w * r[lane + 128];
            a3 += w * r[lane + 192];
            if (tail) a4 += w * r[lane + 256];
        }
    } else {   // overflow fallback (P~1e-20): ebits/ballot path
        const unsigned long long* eb = ebits + (size_t)gw * 16;
#pragma unroll
        for (int c = 0; c < 16; ++c) {
            int n0 = c << 6;
            float wv = e1b[n0 + lane];
            unsigned long long bal = eb[c];
            while (bal) {
                int jj = (int)__ffsll(bal) - 1;
                bal &= bal - 1ull;
                float w = __shfl(wv, jj);
                const float* row = Xb + (size_t)(n0 + jj) * CD;
                den += w;
                a0 += w * row[lane];
                a1 += w * row[lane + 64];
                a2 += w * row[lane + 128];
                a3 += w * row[lane + 192];
                if (tail) a4 += w * row[lane + 256];
            }
        }
    }
    float inv = deg > 0 ? 1.f / den : 0.f;
    float o0 = a0 * inv, o1 = a1 * inv, o2 = a2 * inv, o3 = a3 * inv;
    float o4 = tail ? a4 * inv : 0.f;
    float* erow = edge + (size_t)gw * EP;
    erow[lane]       = o0;
    erow[lane + 64]  = o1;
    erow[lane + 128] = o2;
    erow[lane + 192] = o3;
    erow[lane + 256] = o4;
    float d2 = o0 * qvec[lane];
    d2 += o1 * qvec[lane + 64];
    d2 += o2 * qvec[lane + 128];
    d2 += o3 * qvec[lane + 192];
    if (tail) d2 += o4 * qvec[lane + 256];
    for (int o = 32; o; o >>= 1) d2 += __shfl_down(d2, o);
    if (lane == 0) q[gw] = d2;
}

// ---------- fused node attention (R8-proven): nbits masks + compacted weights ----------
#define ACC16(vv, ww) do { \
    acc[0][0] += (ww).x * (vv).x; acc[0][1] += (ww).x * (vv).y; \
    acc[0][2] += (ww).x * (vv).z; acc[0][3] += (ww).x * (vv).w; \
    acc[1][0] += (ww).y * (vv).x; acc[1][1] += (ww).y * (vv).y; \
    acc[1][2] += (ww).y * (vv).z; acc[1][3] += (ww).y * (vv).w; \
    acc[2][0] += (ww).z * (vv).x; acc[2][1] += (ww).z * (vv).y; \
    acc[2][2] += (ww).z * (vv).z; acc[2][3] += (ww).z * (vv).w; \
    acc[3][0] += (ww).w * (vv).x; acc[3][1] += (ww).w * (vv).y; \
    acc[3][2] += (ww).w * (vv).z; acc[3][3] += (ww).w * (vv).w; \
} while (0)

__global__ __launch_bounds__(320) void k_node_attn(const unsigned long long* __restrict__ nbits,
        const float* __restrict__ p, const float* __restrict__ q,
        const float* __restrict__ edge, float alpha, int do_elu, float* __restrict__ out) {
    __shared__ float4 wsc[4][UCAP];
    __shared__ __align__(8) unsigned short ul[4][UCAP];
    __shared__ int ucnt_s[4], flag_s[4];
    __shared__ float gpn[16], gmx[16], gsc[16];
    __shared__ int gct[16];
    int blk = blockIdx.x;
    int b = blk >> 6, n0 = (blk & 63) << 4;
    int tid = threadIdx.x, wv = tid >> 6, lane = tid & 63;
    const float* qb = q + b * CE;

    if (wv < 4) {
        float pn[4]; const unsigned long long* nb[4];
#pragma unroll
        for (int k = 0; k < 4; ++k) {
            int n = n0 + 4 * wv + k;
            pn[k] = p[b * CN + n];
            nb[k] = nbits + ((size_t)b * CN + n) * 8;
        }
        float sc[4][8];
        int cnt[4] = {0, 0, 0, 0};
        float mx[4] = {-3.4e38f, -3.4e38f, -3.4e38f, -3.4e38f};
        int ubits = 0;
#pragma unroll
        for (int j = 0; j < 8; ++j) {
            int e = lane + (j << 6);
            float qe = qb[e];
            int many = 0;
#pragma unroll
            for (int k = 0; k < 4; ++k) {
                int m = (int)((nb[k][j] >> lane) & 1ull);
                float v = pn[k] + qe;
                v = v > 0.f ? v : alpha * v;
                v = m ? v : -3.0e38f;
                cnt[k] += m; many |= m;
                mx[k] = fmaxf(mx[k], v);
                sc[k][j] = v;
            }
            ubits |= (many ? 1 : 0) << j;
        }
#pragma unroll
        for (int k = 0; k < 4; ++k) {
            for (int o = 32; o; o >>= 1) {
                mx[k] = fmaxf(mx[k], __shfl_xor(mx[k], o));
                cnt[k] += __shfl_xor(cnt[k], o);
            }
        }
        float scale[4];
#pragma unroll
        for (int k = 0; k < 4; ++k) {
            float s = 0.f;
#pragma unroll
            for (int j = 0; j < 8; ++j) { float w8 = __expf(sc[k][j] - mx[k]); sc[k][j] = w8; s += w8; }
            for (int o = 32; o; o >>= 1) s += __shfl_xor(s, o);
            scale[k] = cnt[k] > 0 ? 1.f / s : 1.f;
        }
        int base = 0;
        unsigned long long lmask = (1ull << lane) - 1ull;
#pragma unroll
        for (int j = 0; j < 8; ++j) {
            unsigned long long bal = __ballot((ubits >> j) & 1);
            if ((ubits >> j) & 1) {
                int off = base + (int)__popcll(bal & lmask);
                if (off < UCAP) {
                    ul[wv][off] = (unsigned short)(lane + (j << 6));
                    wsc[wv][off] = make_float4(sc[0][j] * scale[0], sc[1][j] * scale[1],
                                               sc[2][j] * scale[2], sc[3][j] * scale[3]);
                }
            }
            base += (int)__popcll(bal);
        }
        if (lane == 0) {
            ucnt_s[wv] = base < UCAP ? base : UCAP;
            flag_s[wv] = (cnt[0] == 0) | (cnt[1] == 0) | (cnt[2] == 0) | (cnt[3] == 0) |
                         (base > UCAP);
            gpn[wv*4+0]=pn[0]; gmx[wv*4+0]=mx[0]; gsc[wv*4+0]=scale[0]; gct[wv*4+0]=cnt[0];
            gpn[wv*4+1]=pn[1]; gmx[wv*4+1]=mx[1]; gsc[wv*4+1]=scale[1]; gct[wv*4+1]=cnt[1];
            gpn[wv*4+2]=pn[2]; gmx[wv*4+2]=mx[2]; gsc[wv*4+2]=scale[2]; gct[wv*4+2]=cnt[2];
            gpn[wv*4+3]=pn[3]; gmx[wv*4+3]=mx[3]; gsc[wv*4+3]=scale[3]; gct[wv*4+3]=cnt[3];
        }
    }
    __syncthreads();

    int grp = tid / 80;
    int j4 = tid - grp * 80;
    const float4* eb4 = reinterpret_cast<const float4*>(edge + (size_t)b * CE * EP) + j4;
    int cnt = ucnt_s[grp], bad = flag_s[grp];
    float acc[4][4] = {};
    if (!bad) {
        int i = 0;
        for (; i + 8 <= cnt; i += 8) {
            ushort4 ua = *reinterpret_cast<const ushort4*>(&ul[grp][i]);
            ushort4 ub = *reinterpret_cast<const ushort4*>(&ul[grp][i + 4]);
            float4 v0 = eb4[(size_t)ua.x * 80], v1 = eb4[(size_t)ua.y * 80];
            float4 v2 = eb4[(size_t)ua.z * 80], v3 = eb4[(size_t)ua.w * 80];
            float4 v4 = eb4[(size_t)ub.x * 80], v5 = eb4[(size_t)ub.y * 80];
            float4 v6 = eb4[(size_t)ub.z * 80], v7 = eb4[(size_t)ub.w * 80];
            { float4 w = wsc[grp][i];     ACC16(v0, w); }
            { float4 w = wsc[grp][i + 1]; ACC16(v1, w); }
            { float4 w = wsc[grp][i + 2]; ACC16(v2, w); }
            { float4 w = wsc[grp][i + 3]; ACC16(v3, w); }
            { float4 w = wsc[grp][i + 4]; ACC16(v4, w); }
            { float4 w = wsc[grp][i + 5]; ACC16(v5, w); }
            { float4 w = wsc[grp][i + 6]; ACC16(v6, w); }
            { float4 w = wsc[grp][i + 7]; ACC16(v7, w); }
        }
        for (; i < cnt; ++i) {
            int e = ul[grp][i];
            float4 v = eb4[(size_t)e * 80];
            float4 w = wsc[grp][i];
            ACC16(v, w);
        }
    } else {
        float pnk[4], mxk[4], sck[4]; int ctk[4];
        const unsigned long long* nbr[4];
#pragma unroll
        for (int k = 0; k < 4; ++k) {
            pnk[k] = gpn[grp*4+k]; mxk[k] = gmx[grp*4+k]; sck[k] = gsc[grp*4+k]; ctk[k] = gct[grp*4+k];
            nbr[k] = nbits + ((size_t)b * CN + n0 + grp * 4 + k) * 8;
        }
        for (int e = 0; e < CE; ++e) {
            float4 v = eb4[(size_t)e * 80];
            float qe = qb[e];
#pragma unroll
            for (int k = 0; k < 4; ++k) {
                int m = (int)((nbr[k][e >> 6] >> (e & 63)) & 1ull);
                float vv = pnk[k] + qe; vv = vv > 0.f ? vv : alpha * vv;
                float w = ctk[k] == 0 ? (1.f / CE) : (m ? __expf(vv - mxk[k]) * sck[k] : 0.f);
                acc[k][0] += w * v.x; acc[k][1] += w * v.y; acc[k][2] += w * v.z; acc[k][3] += w * v.w;
            }
        }
    }
    if (j4 < 75) {
#pragma unroll
        for (int ni = 0; ni < 4; ++ni) {
            float4 o = {acc[ni][0], acc[ni][1], acc[ni][2], acc[ni][3]};
            if (do_elu) {
                o.x = o.x > 0.f ? o.x : expm1f(o.x);
                o.y = o.y > 0.f ? o.y : expm1f(o.y);
                o.z = o.z > 0.f ? o.z : expm1f(o.z);
                o.w = o.w > 0.f ? o.w : expm1f(o.w);
            }
            *reinterpret_cast<float4*>(out + ((size_t)b * CN + n0 + grp * 4 + ni) * CD + j4 * 4) = o;
        }
    }
}

extern "C" void kernel_launch(void* const* d_in, const int* in_sizes, int n_in,
                              void* d_out, int out_size, void* d_ws, size_t ws_size,
                              hipStream_t stream) {
    const int*   inputs = (const int*)d_in[0];
    const int*   HT     = (const int*)d_in[1];
    const float* emb    = (const float*)d_in[2];
    const float* w2_1   = (const float*)d_in[3];
    const float* w3_1   = (const float*)d_in[4];
    const float* a_1    = (const float*)d_in[5];
    const float* a2_1   = (const float*)d_in[6];
    const float* wc_1   = (const float*)d_in[7];
    const float* w_2    = (const float*)d_in[8];
    const float* w2_2   = (const float*)d_in[9];
    const float* w3_2   = (const float*)d_in[10];
    const float* a_2    = (const float*)d_in[11];
    const float* a2_2   = (const float*)d_in[12];
    const float* wc_2   = (const float*)d_in[13];

    char* ws = (char*)d_ws;
    float* big0               = (float*)(ws);                          // 39,321,600 B: X0 -> X1
    float* big1               = (float*)(ws + 39321600);               // 39,321,600 B: XW
    float* edge               = (float*)(ws + 78643200);               // 20,971,520 B (EP=320)
    unsigned long long* ebits = (unsigned long long*)(ws + 99614720);  //  2,097,152 B
    unsigned long long* nbits = (unsigned long long*)(ws + 101711872); //  2,097,152 B
    unsigned short* mem       = (unsigned short*)(ws + 103809024);     //  6,291,456 B
    int* degs                 = (int*)(ws + 110100480);                //     65,536 B
    float* s1                 = (float*)(ws + 110166016);              //    131,072 B
    float* p                  = (float*)(ws + 110297088);              //    131,072 B
    float* e1                 = (float*)(ws + 110428160);              //    131,072 B
    float* qv                 = (float*)(ws + 110559232);              //     65,536 B
    float* vecs               = (float*)(ws + 110624768);              //      7,200 B
    // total: 110,631,968 B

    k_embed<<<9600, 256, 0, stream>>>(inputs, emb, big0);
    k_ebits_mem<<<4096, 256, 0, stream>>>(HT, ebits, mem, degs);
    k_bitT<<<512, 512, 0, stream>>>(ebits, nbits);
    k_prep<<<6, 320, 0, stream>>>(w2_1, w3_1, a_1, a2_1, w2_2, w3_2, a_2, a2_2, vecs);

    // ---- layer 1: transfer=False, concat=True (ELU), alpha=0.1 ----
    k_score<<<CB * CN / 4, 256, 0, stream>>>(big0, vecs, vecs + CD, wc_1, a_1, 0.1f, s1, p, CB * CN);
    k_bmax<<<CB, 1024, 0, stream>>>(s1, e1);
    k_edge_agg<<<4096, 256, 0, stream>>>(mem, degs, ebits, e1, big0, vecs + 2 * CD, edge, qv);
    k_node_attn<<<2048, 320, 0, stream>>>(nbits, p, qv, edge, 0.1f, 1, big0);   // X1 -> big0

    // ---- layer 2: transfer=True, concat=False, alpha=0.2 ----
    k_score<<<CB * CN / 4, 256, 0, stream>>>(big0, vecs + 3 * CD, vecs + 4 * CD, wc_2, a_2, 0.2f, s1, p, CB * CN);
    k_gemm300<<<dim3(5, 512), 256, 0, stream>>>(big0, w_2, big1, CB * CN, CD, CD);   // XW = X1 @ w_2
    k_bmax<<<CB, 1024, 0, stream>>>(s1, e1);
    k_edge_agg<<<4096, 256, 0, stream>>>(mem, degs, ebits, e1, big1, vecs + 5 * CD, edge, qv);
    k_node_attn<<<2048, 320, 0, stream>>>(nbits, p, qv, edge, 0.2f, 0, (float*)d_out);
}